// Round 1
// baseline (2168.092 us; speedup 1.0000x reference)
//
#include <hip/hip_runtime.h>

// ---------------------------------------------------------------------------
// Transformer encoder (B=2, S=2048, D=512, H=8, DK=64, DFF=2048, L=6), fp16
// MFMA compute, f32 residual stream. Round-0 baseline: reg-staged 2-phase
// GEMM tiles, transposed flash attention.
// ---------------------------------------------------------------------------

typedef _Float16 f16;
typedef _Float16 f16x8 __attribute__((ext_vector_type(8)));
typedef _Float16 f16x4 __attribute__((ext_vector_type(4)));
typedef float    f32x4 __attribute__((ext_vector_type(4)));

#define MFMA16(a, b, c) __builtin_amdgcn_mfma_f32_16x16x32_f16((a), (b), (c), 0, 0, 0)

static constexpr int Dm  = 512;
static constexpr int Hh  = 8;
static constexpr int Sx  = 2048;
static constexpr int NTOK = 4096;   // B*S
static constexpr int DFFm = 2048;
static constexpr int Lc  = 6;

// ---------------------------------------------------------------- transpose+cvt
// out[z][c][r] = (f16) in[z][r][c]
__global__ __launch_bounds__(256) void transpose_cvt(
    const float* __restrict__ in, f16* __restrict__ out, int R, int C)
{
  __shared__ float t[32][33];
  const int z = blockIdx.z;
  const float* src = in + (size_t)z * R * C;
  f16* dst = out + (size_t)z * R * C;
  const int r0 = blockIdx.y * 32, c0 = blockIdx.x * 32;
  const int tx = threadIdx.x, ty = threadIdx.y;
  #pragma unroll
  for (int i = 0; i < 4; i++)
    t[ty + i * 8][tx] = src[(size_t)(r0 + ty + i * 8) * C + c0 + tx];
  __syncthreads();
  #pragma unroll
  for (int i = 0; i < 4; i++)
    dst[(size_t)(c0 + ty + i * 8) * R + r0 + tx] = (f16)t[tx][ty + i * 8];
}

// ---------------------------------------------------------------- embedding
__global__ __launch_bounds__(256) void embed_k(
    const int* __restrict__ src, const float* __restrict__ emb,
    const float* __restrict__ pe, float* __restrict__ x)
{
  const int gid = blockIdx.x * 256 + threadIdx.x;
  const int token = gid >> 6;
  const int d0 = (gid & 63) << 3;
  const int s = token & (Sx - 1);
  const int tk = src[token];
  const float* e = emb + (size_t)tk * Dm + d0;
  const float* p = pe + (size_t)s * Dm + d0;
  float* o = x + (size_t)token * Dm + d0;
  const float SC = 22.627416997969522f;  // sqrt(512)
  #pragma unroll
  for (int j = 0; j < 8; j++) o[j] = e[j] * SC + p[j];
}

// ---------------------------------------------------------------- layernorm
// one wave per row of 512; OUT = f16 (hidden) or float (final output)
template <typename OUT>
__global__ __launch_bounds__(256) void ln_k(
    const float* __restrict__ x, const float* __restrict__ sc,
    const float* __restrict__ bi, OUT* __restrict__ out)
{
  const int row = blockIdx.x * 4 + (threadIdx.x >> 6);
  const int l = threadIdx.x & 63;
  const float* px = x + (size_t)row * Dm + l * 8;
  float v[8];
  *(float4*)&v[0] = *(const float4*)px;
  *(float4*)&v[4] = *(const float4*)(px + 4);
  float s = 0.f;
  #pragma unroll
  for (int j = 0; j < 8; j++) s += v[j];
  #pragma unroll
  for (int m = 1; m < 64; m <<= 1) s += __shfl_xor(s, m);
  const float mu = s * (1.0f / 512.0f);
  float qv = 0.f;
  #pragma unroll
  for (int j = 0; j < 8; j++) { float d = v[j] - mu; qv += d * d; }
  #pragma unroll
  for (int m = 1; m < 64; m <<= 1) qv += __shfl_xor(qv, m);
  const float inv = rsqrtf(qv * (1.0f / 512.0f) + 1e-5f);
  float scv[8], biv[8];
  *(float4*)&scv[0] = *(const float4*)(sc + l * 8);
  *(float4*)&scv[4] = *(const float4*)(sc + l * 8 + 4);
  *(float4*)&biv[0] = *(const float4*)(bi + l * 8);
  *(float4*)&biv[4] = *(const float4*)(bi + l * 8 + 4);
  if constexpr (sizeof(OUT) == 2) {
    f16x8 o;
    #pragma unroll
    for (int j = 0; j < 8; j++) o[j] = (f16)((v[j] - mu) * inv * scv[j] + biv[j]);
    *(f16x8*)((f16*)out + (size_t)row * Dm + l * 8) = o;
  } else {
    float o[8];
    #pragma unroll
    for (int j = 0; j < 8; j++) o[j] = (v[j] - mu) * inv * scv[j] + biv[j];
    float* po = (float*)out + (size_t)row * Dm + l * 8;
    *(float4*)po = *(float4*)&o[0];
    *(float4*)(po + 4) = *(float4*)&o[4];
  }
}

// ---------------------------------------------------------------- GEMM
// C[M=4096][N] = A[M][K] * Bt[N][K]^T ; 2-phase LDS, reg-staged, prefetch.
// MODE 0: out=f16          (QKV; z selects B/out among 3)
// MODE 1: xio += acc       (WO + residual, f32)
// MODE 2: out=f16 relu(acc+bias)   (W1)
// MODE 3: xio += acc+bias  (W2 + residual, f32)
template <int BN, int MODE>
__global__ __launch_bounds__(256) void gemm_k(
    const f16* __restrict__ A,
    const f16* __restrict__ B0, const f16* __restrict__ B1, const f16* __restrict__ B2,
    f16* __restrict__ O0, f16* __restrict__ O1, f16* __restrict__ O2,
    float* __restrict__ xio, const float* __restrict__ bias,
    int N, int K)
{
  constexpr int BM = 128;
  constexpr int NF = BN / 32;              // frags per wave in N
  __shared__ f16 lsA[BM * 64];
  __shared__ f16 lsB[BN * 64];
  const int tid = threadIdx.x;
  const int l = tid & 63, w = tid >> 6;
  const int lr = l & 15, lh = l >> 4;
  const int wm = w >> 1, wn = w & 1;
  const int bm = blockIdx.x, bn = blockIdx.y, z = blockIdx.z;
  const f16* Bt = (z == 0) ? B0 : ((z == 1) ? B1 : B2);
  f16* Oz = (z == 0) ? O0 : ((z == 1) ? O1 : O2);

  constexpr int ACH = (BM * 64) / (256 * 8);   // 4 chunks of 16B per thread
  constexpr int BCH = (BN * 64) / (256 * 8);   // 2 or 4
  int4 ra[ACH], rb[BCH];
  const size_t rowA0 = (size_t)bm * BM;
  const size_t rowB0 = (size_t)bn * BN;

  auto load = [&](int kt) {
    #pragma unroll
    for (int i = 0; i < ACH; i++) {
      int c = i * 256 + tid;
      ra[i] = *(const int4*)(A + (rowA0 + (c >> 3)) * K + kt * 64 + (c & 7) * 8);
    }
    #pragma unroll
    for (int i = 0; i < BCH; i++) {
      int c = i * 256 + tid;
      rb[i] = *(const int4*)(Bt + (rowB0 + (c >> 3)) * K + kt * 64 + (c & 7) * 8);
    }
  };

  f32x4 acc[4][NF] = {};
  load(0);
  const int NT = K >> 6;
  for (int kt = 0; kt < NT; ++kt) {
    __syncthreads();
    #pragma unroll
    for (int i = 0; i < ACH; i++) *(int4*)(lsA + (i * 256 + tid) * 8) = ra[i];
    #pragma unroll
    for (int i = 0; i < BCH; i++) *(int4*)(lsB + (i * 256 + tid) * 8) = rb[i];
    __syncthreads();
    if (kt + 1 < NT) load(kt + 1);
    #pragma unroll
    for (int s = 0; s < 2; s++) {
      f16x8 af[4], bf[NF];
      #pragma unroll
      for (int mf = 0; mf < 4; mf++)
        af[mf] = *(const f16x8*)(lsA + (wm * 64 + mf * 16 + lr) * 64 + s * 32 + lh * 8);
      #pragma unroll
      for (int nf = 0; nf < NF; nf++)
        bf[nf] = *(const f16x8*)(lsB + (wn * (BN / 2) + nf * 16 + lr) * 64 + s * 32 + lh * 8);
      #pragma unroll
      for (int mf = 0; mf < 4; mf++)
        #pragma unroll
        for (int nf = 0; nf < NF; nf++)
          acc[mf][nf] = MFMA16(af[mf], bf[nf], acc[mf][nf]);
    }
  }

  #pragma unroll
  for (int mf = 0; mf < 4; mf++) {
    #pragma unroll
    for (int nf = 0; nf < NF; nf++) {
      const int token = bm * BM + wm * 64 + mf * 16 + lh * 4;
      const int ch = bn * BN + wn * (BN / 2) + nf * 16 + lr;
      #pragma unroll
      for (int r = 0; r < 4; r++) {
        float v = acc[mf][nf][r];
        size_t idx = (size_t)(token + r) * N + ch;
        if constexpr (MODE == 0) {
          Oz[idx] = (f16)v;
        } else if constexpr (MODE == 1) {
          xio[idx] += v;
        } else if constexpr (MODE == 2) {
          v += bias[ch];
          Oz[idx] = (f16)fmaxf(v, 0.f);
        } else {
          xio[idx] += v + bias[ch];
        }
      }
    }
  }
}

// ---------------------------------------------------------------- V transpose
// vt[(b*8+h)*64 + dv][s] = v[b*2048 + s][h*64 + dv]
__global__ __launch_bounds__(256) void vtrans_k(
    const f16* __restrict__ v, f16* __restrict__ vt)
{
  __shared__ f16 t[64][80];   // row stride 160B: 16B-aligned, bank-rotating
  const int tid = threadIdx.x;
  const int st = blockIdx.x, bh = blockIdx.y;
  const int b = bh >> 3, h = bh & 7;
  #pragma unroll
  for (int i = 0; i < 2; i++) {
    int c = i * 256 + tid; int s = c >> 3, sl = c & 7;
    *(int4*)&t[s][sl * 8] =
        *(const int4*)(v + (size_t)(b * Sx + st * 64 + s) * Dm + h * 64 + sl * 8);
  }
  __syncthreads();
  #pragma unroll
  for (int i = 0; i < 2; i++) {
    int c = i * 256 + tid; int dv = c >> 3, sl = c & 7;
    f16 tmp[8];
    #pragma unroll
    for (int j = 0; j < 8; j++) tmp[j] = t[sl * 8 + j][dv];
    *(int4*)(vt + (size_t)(bh * 64 + dv) * Sx + st * 64 + sl * 8) = *(const int4*)tmp;
  }
}

// ---------------------------------------------------------------- attention
// Transposed flash attention. Block: 256 thr = 4 waves; each wave owns 32
// queries (2 frags of 16); block covers 128 queries of one (b,h).
// S^T = K @ Q^T (lane owns query col = lane&15), O^T = V^T @ P^T.
__global__ __launch_bounds__(256) void attn_k(
    const f16* __restrict__ q, const f16* __restrict__ kk,
    const f16* __restrict__ vt, const int* __restrict__ src,
    f16* __restrict__ out)
{
  __shared__ f16 lsK[64 * 64];
  __shared__ f16 lsV[64 * 64];   // V^T tile: [dv][key]
  const int tid = threadIdx.x;
  const int l = tid & 63, w = tid >> 6;
  const int lr = l & 15, lh = l >> 4;
  const int qt = blockIdx.x;     // 0..15
  const int bh = blockIdx.y;     // 0..15
  const int b = bh >> 3, h = bh & 7;

  // Q fragments, pre-scaled by 1/sqrt(DK)=0.125 (exact: power of two)
  f16x8 qf[2][2];
  #pragma unroll
  for (int s = 0; s < 2; s++)
    #pragma unroll
    for (int j = 0; j < 2; j++) {
      size_t row = (size_t)(b * Sx + qt * 128 + w * 32 + j * 16 + lr);
      f16x8 t = *(const f16x8*)(q + row * Dm + h * 64 + s * 32 + lh * 8);
      qf[s][j] = t * (_Float16)0.125f;
    }

  f32x4 oacc[4][2] = {};
  float mrun[2] = {-1e30f, -1e30f};
  float lrun[2] = {0.f, 0.f};

  int4 rk[2], rv[2];
  auto loadKV = [&](int kt) {
    #pragma unroll
    for (int i = 0; i < 2; i++) {
      int c = i * 256 + tid;
      rk[i] = *(const int4*)(kk + (size_t)(b * Sx + kt * 64 + (c >> 3)) * Dm + h * 64 + (c & 7) * 8);
      rv[i] = *(const int4*)(vt + (size_t)(bh * 64 + (c >> 3)) * Sx + kt * 64 + (c & 7) * 8);
    }
  };
  loadKV(0);

  for (int kt = 0; kt < 32; ++kt) {
    __syncthreads();
    #pragma unroll
    for (int i = 0; i < 2; i++) {
      *(int4*)(lsK + (i * 256 + tid) * 8) = rk[i];
      *(int4*)(lsV + (i * 256 + tid) * 8) = rv[i];
    }
    __syncthreads();
    if (kt < 31) loadKV(kt + 1);

    // ---- S^T = K @ Q^T  (f32)
    f32x4 sacc[4][2] = {};
    #pragma unroll
    for (int s = 0; s < 2; s++) {
      #pragma unroll
      for (int kf = 0; kf < 4; kf++) {
        f16x8 a = *(const f16x8*)(lsK + (kf * 16 + lr) * 64 + s * 32 + lh * 8);
        #pragma unroll
        for (int j = 0; j < 2; j++)
          sacc[kf][j] = MFMA16(a, qf[s][j], sacc[kf][j]);
      }
    }
    // ---- key padding mask (key index = kt*64 + kf*16 + lh*4 + r)
    #pragma unroll
    for (int kf = 0; kf < 4; kf++) {
      int4 m4 = *(const int4*)(src + b * Sx + kt * 64 + kf * 16 + lh * 4);
      const int* mp = (const int*)&m4;
      #pragma unroll
      for (int r = 0; r < 4; r++)
        if (mp[r] == 0) { sacc[kf][0][r] = -1e30f; sacc[kf][1][r] = -1e30f; }
    }
    // ---- online softmax per query frag; lane owns query = lane&15
    f16x8 pa[2][2];
    #pragma unroll
    for (int j = 0; j < 2; j++) {
      float mx = -1e30f;
      #pragma unroll
      for (int kf = 0; kf < 4; kf++)
        #pragma unroll
        for (int r = 0; r < 4; r++) mx = fmaxf(mx, sacc[kf][j][r]);
      mx = fmaxf(mx, __shfl_xor(mx, 16));
      mx = fmaxf(mx, __shfl_xor(mx, 32));
      const float mnew = fmaxf(mrun[j], mx);
      const float resc = __expf(mrun[j] - mnew);
      float ps = 0.f;
      #pragma unroll
      for (int kf = 0; kf < 4; kf++)
        #pragma unroll
        for (int r = 0; r < 4; r++) {
          float p = __expf(sacc[kf][j][r] - mnew);
          sacc[kf][j][r] = p;
          ps += p;
        }
      ps += __shfl_xor(ps, 16);
      ps += __shfl_xor(ps, 32);
      lrun[j] = lrun[j] * resc + ps;
      mrun[j] = mnew;
      #pragma unroll
      for (int mf = 0; mf < 4; mf++) oacc[mf][j] *= resc;
      // pack P^T: element jj -> key = 32s + 16*(jj>>2) + lh*4 + (jj&3)
      #pragma unroll
      for (int s = 0; s < 2; s++)
        #pragma unroll
        for (int jj = 0; jj < 8; jj++)
          pa[s][j][jj] = (f16)sacc[2 * s + (jj >> 2)][j][jj & 3];
    }
    // ---- O^T += V^T @ P^T  (A elem jj -> same key bijection as pa)
    #pragma unroll
    for (int s = 0; s < 2; s++) {
      #pragma unroll
      for (int mf = 0; mf < 4; mf++) {
        union { f16x8 v8; f16x4 v4[2]; } u;
        const f16* vp = lsV + (mf * 16 + lr) * 64 + s * 32 + lh * 4;
        u.v4[0] = *(const f16x4*)vp;
        u.v4[1] = *(const f16x4*)(vp + 16);
        #pragma unroll
        for (int j = 0; j < 2; j++)
          oacc[mf][j] = MFMA16(u.v8, pa[s][j], oacc[mf][j]);
      }
    }
  }

  // ---- write O: lane's q = lane&15; dv = mf*16 + lh*4 + r
  #pragma unroll
  for (int j = 0; j < 2; j++) {
    const float inv = 1.f / lrun[j];
    size_t row = (size_t)(b * Sx + qt * 128 + w * 32 + j * 16 + lr);
    #pragma unroll
    for (int mf = 0; mf < 4; mf++) {
      f16x4 o;
      #pragma unroll
      for (int r = 0; r < 4; r++) o[r] = (f16)(oacc[mf][j][r] * inv);
      *(f16x4*)(out + row * Dm + h * 64 + mf * 16 + lh * 4) = o;
    }
  }
}

// ---------------------------------------------------------------- launch
extern "C" void kernel_launch(void* const* d_in, const int* in_sizes, int n_in,
                              void* d_out, int out_size, void* d_ws, size_t ws_size,
                              hipStream_t stream)
{
  (void)in_sizes; (void)n_in; (void)out_size; (void)ws_size;
  const int*   src  = (const int*)d_in[0];
  const float* emb  = (const float*)d_in[1];
  const float* pe   = (const float*)d_in[2];
  const float* WQ   = (const float*)d_in[3];
  const float* WK   = (const float*)d_in[4];
  const float* WV   = (const float*)d_in[5];
  const float* WO   = (const float*)d_in[6];
  const float* W1   = (const float*)d_in[7];
  const float* b1   = (const float*)d_in[8];
  const float* W2   = (const float*)d_in[9];
  const float* b2   = (const float*)d_in[10];
  const float* ln1s = (const float*)d_in[11];
  const float* ln1b = (const float*)d_in[12];
  const float* ln2s = (const float*)d_in[13];
  const float* ln2b = (const float*)d_in[14];
  const float* fns  = (const float*)d_in[15];
  const float* fnb  = (const float*)d_in[16];

  char* ws = (char*)d_ws;
  const size_t DD = (size_t)Dm * Dm;           // 262144
  const size_t DF = (size_t)Dm * DFFm;         // 1048576
  f16* wtQ = (f16*)(ws);                        // [L][512][512]
  f16* wtK = wtQ + Lc * DD;
  f16* wtV = wtK + Lc * DD;
  f16* wtO = wtV + Lc * DD;
  f16* wt1 = wtO + Lc * DD;                     // [L][2048][512]
  f16* wt2 = wt1 + Lc * DF;                     // [L][512][2048]
  float* x  = (float*)(wt2 + Lc * DF);          // [4096][512] f32
  f16* hbuf = (f16*)(x + (size_t)NTOK * Dm);    // [4096][512]
  f16* qb   = hbuf + (size_t)NTOK * Dm;
  f16* kb   = qb + (size_t)NTOK * Dm;
  f16* vraw = kb + (size_t)NTOK * Dm;
  f16* vtb  = vraw + (size_t)NTOK * Dm;         // [16][64][2048]
  f16* attn = vtb + (size_t)NTOK * Dm;
  f16* ff   = attn + (size_t)NTOK * Dm;         // [4096][2048]

  const dim3 tb(32, 8);
  transpose_cvt<<<dim3(16, 16, Lc), tb, 0, stream>>>(WQ, wtQ, Dm, Dm);
  transpose_cvt<<<dim3(16, 16, Lc), tb, 0, stream>>>(WK, wtK, Dm, Dm);
  transpose_cvt<<<dim3(16, 16, Lc), tb, 0, stream>>>(WV, wtV, Dm, Dm);
  transpose_cvt<<<dim3(16, 16, Lc), tb, 0, stream>>>(WO, wtO, Dm, Dm);
  transpose_cvt<<<dim3(64, 16, Lc), tb, 0, stream>>>(W1, wt1, Dm, DFFm);
  transpose_cvt<<<dim3(16, 64, Lc), tb, 0, stream>>>(W2, wt2, DFFm, Dm);

  embed_k<<<1024, 256, 0, stream>>>(src, emb, pe, x);

  for (int l = 0; l < Lc; l++) {
    const f16* wq = wtQ + (size_t)l * DD;
    const f16* wk = wtK + (size_t)l * DD;
    const f16* wv = wtV + (size_t)l * DD;
    const f16* wo = wtO + (size_t)l * DD;
    const f16* w1 = wt1 + (size_t)l * DF;
    const f16* w2 = wt2 + (size_t)l * DF;

    ln_k<f16><<<1024, 256, 0, stream>>>(x, ln1s + l * Dm, ln1b + l * Dm, hbuf);
    gemm_k<64, 0><<<dim3(32, 8, 3), 256, 0, stream>>>(
        hbuf, wq, wk, wv, qb, kb, vraw, nullptr, nullptr, Dm, Dm);
    vtrans_k<<<dim3(32, 16), 256, 0, stream>>>(vraw, vtb);
    attn_k<<<dim3(16, 16), 256, 0, stream>>>(qb, kb, vtb, src, attn);
    gemm_k<64, 1><<<dim3(32, 8, 1), 256, 0, stream>>>(
        attn, wo, wo, wo, nullptr, nullptr, nullptr, x, nullptr, Dm, Dm);
    ln_k<f16><<<1024, 256, 0, stream>>>(x, ln2s + l * Dm, ln2b + l * Dm, hbuf);
    gemm_k<128, 2><<<dim3(32, 16, 1), 256, 0, stream>>>(
        hbuf, w1, w1, w1, ff, ff, ff, nullptr, b1 + (size_t)l * DFFm, DFFm, Dm);
    gemm_k<64, 3><<<dim3(32, 8, 1), 256, 0, stream>>>(
        ff, w2, w2, w2, nullptr, nullptr, nullptr, x, b2 + (size_t)l * Dm, Dm, DFFm);
  }

  ln_k<float><<<1024, 256, 0, stream>>>(x, fns, fnb, (float*)d_out);
}

// Round 2
// 1020.783 us; speedup vs baseline: 2.1239x; 2.1239x over previous
//
#include <hip/hip_runtime.h>

// ---------------------------------------------------------------------------
// Transformer encoder (B=2, S=2048, D=512, H=8, DK=64, DFF=2048, L=6), fp16
// MFMA compute, f32 residual stream.
// R2: global_load_lds(16B) staging everywhere; attention K/V LDS XOR-swizzled
// via pre-swizzled global source (rule #21: swizzle source+read, linear dest);
// attention double-buffered, 1 barrier/tile.
// ---------------------------------------------------------------------------

typedef _Float16 f16;
typedef _Float16 f16x8 __attribute__((ext_vector_type(8)));
typedef _Float16 f16x4 __attribute__((ext_vector_type(4)));
typedef float    f32x4 __attribute__((ext_vector_type(4)));

#define MFMA16(a, b, c) __builtin_amdgcn_mfma_f32_16x16x32_f16((a), (b), (c), 0, 0, 0)
#define GLOAD_LDS16(GP, LP)                                        \
  __builtin_amdgcn_global_load_lds(                                \
      (const __attribute__((address_space(1))) void*)(GP),         \
      (__attribute__((address_space(3))) void*)(LP), 16, 0, 0)

static constexpr int Dm  = 512;
static constexpr int Sx  = 2048;
static constexpr int NTOK = 4096;   // B*S
static constexpr int DFFm = 2048;
static constexpr int Lc  = 6;

// ---------------------------------------------------------------- transpose+cvt
// out[z][c][r] = (f16) in[z][r][c]
__global__ __launch_bounds__(256) void transpose_cvt(
    const float* __restrict__ in, f16* __restrict__ out, int R, int C)
{
  __shared__ float t[32][33];
  const int z = blockIdx.z;
  const float* src = in + (size_t)z * R * C;
  f16* dst = out + (size_t)z * R * C;
  const int r0 = blockIdx.y * 32, c0 = blockIdx.x * 32;
  const int tx = threadIdx.x, ty = threadIdx.y;
  #pragma unroll
  for (int i = 0; i < 4; i++)
    t[ty + i * 8][tx] = src[(size_t)(r0 + ty + i * 8) * C + c0 + tx];
  __syncthreads();
  #pragma unroll
  for (int i = 0; i < 4; i++)
    dst[(size_t)(c0 + ty + i * 8) * R + r0 + tx] = (f16)t[tx][ty + i * 8];
}

// ---------------------------------------------------------------- embedding
__global__ __launch_bounds__(256) void embed_k(
    const int* __restrict__ src, const float* __restrict__ emb,
    const float* __restrict__ pe, float* __restrict__ x)
{
  const int gid = blockIdx.x * 256 + threadIdx.x;
  const int token = gid >> 6;
  const int d0 = (gid & 63) << 3;
  const int s = token & (Sx - 1);
  const int tk = src[token];
  const float* e = emb + (size_t)tk * Dm + d0;
  const float* p = pe + (size_t)s * Dm + d0;
  float* o = x + (size_t)token * Dm + d0;
  const float SC = 22.627416997969522f;  // sqrt(512)
  #pragma unroll
  for (int j = 0; j < 8; j++) o[j] = e[j] * SC + p[j];
}

// ---------------------------------------------------------------- layernorm
template <typename OUT>
__global__ __launch_bounds__(256) void ln_k(
    const float* __restrict__ x, const float* __restrict__ sc,
    const float* __restrict__ bi, OUT* __restrict__ out)
{
  const int row = blockIdx.x * 4 + (threadIdx.x >> 6);
  const int l = threadIdx.x & 63;
  const float* px = x + (size_t)row * Dm + l * 8;
  float v[8];
  *(float4*)&v[0] = *(const float4*)px;
  *(float4*)&v[4] = *(const float4*)(px + 4);
  float s = 0.f;
  #pragma unroll
  for (int j = 0; j < 8; j++) s += v[j];
  #pragma unroll
  for (int m = 1; m < 64; m <<= 1) s += __shfl_xor(s, m);
  const float mu = s * (1.0f / 512.0f);
  float qv = 0.f;
  #pragma unroll
  for (int j = 0; j < 8; j++) { float d = v[j] - mu; qv += d * d; }
  #pragma unroll
  for (int m = 1; m < 64; m <<= 1) qv += __shfl_xor(qv, m);
  const float inv = rsqrtf(qv * (1.0f / 512.0f) + 1e-5f);
  float scv[8], biv[8];
  *(float4*)&scv[0] = *(const float4*)(sc + l * 8);
  *(float4*)&scv[4] = *(const float4*)(sc + l * 8 + 4);
  *(float4*)&biv[0] = *(const float4*)(bi + l * 8);
  *(float4*)&biv[4] = *(const float4*)(bi + l * 8 + 4);
  if constexpr (sizeof(OUT) == 2) {
    f16x8 o;
    #pragma unroll
    for (int j = 0; j < 8; j++) o[j] = (f16)((v[j] - mu) * inv * scv[j] + biv[j]);
    *(f16x8*)((f16*)out + (size_t)row * Dm + l * 8) = o;
  } else {
    float o[8];
    #pragma unroll
    for (int j = 0; j < 8; j++) o[j] = (v[j] - mu) * inv * scv[j] + biv[j];
    float* po = (float*)out + (size_t)row * Dm + l * 8;
    *(float4*)po = *(float4*)&o[0];
    *(float4*)(po + 4) = *(float4*)&o[4];
  }
}

// ---------------------------------------------------------------- GEMM
// C[M=4096][N] = A[M][K] * Bt[N][K]^T ; m97 structure: global_load_lds(16B)
// staging, linear LDS, 2 barriers per K-step.
// MODE 0: out=f16 (QKV, z selects) | 1: xio+=acc | 2: relu(acc+bias)->f16
// MODE 3: xio += acc + bias
template <int BN, int MODE>
__global__ __launch_bounds__(256) void gemm_k(
    const f16* __restrict__ A,
    const f16* __restrict__ B0, const f16* __restrict__ B1, const f16* __restrict__ B2,
    f16* __restrict__ O0, f16* __restrict__ O1, f16* __restrict__ O2,
    float* __restrict__ xio, const float* __restrict__ bias,
    int N, int K)
{
  constexpr int BM = 128;
  constexpr int NF = BN / 32;
  __shared__ f16 lsA[BM * 64];
  __shared__ f16 lsB[BN * 64];
  const int tid = threadIdx.x;
  const int l = tid & 63, w = tid >> 6;
  const int lr = l & 15, lh = l >> 4;
  const int wm = w >> 1, wn = w & 1;
  const int bm = blockIdx.x, bn = blockIdx.y, z = blockIdx.z;
  const f16* Bt = (z == 0) ? B0 : ((z == 1) ? B1 : B2);
  f16* Oz = (z == 0) ? O0 : ((z == 1) ? O1 : O2);

  constexpr int ACH = (BM * 64) / (256 * 8);   // 4
  constexpr int BCH = (BN * 64) / (256 * 8);   // 2 or 4
  const size_t rowA0 = (size_t)bm * BM;
  const size_t rowB0 = (size_t)bn * BN;

  f32x4 acc[4][NF] = {};
  const int NT = K >> 6;
  for (int kt = 0; kt < NT; ++kt) {
    __syncthreads();   // prior tile's LDS reads complete
    #pragma unroll
    for (int i = 0; i < ACH; i++) {
      int c = i * 256 + tid;
      GLOAD_LDS16(A + (rowA0 + (c >> 3)) * K + kt * 64 + (c & 7) * 8, lsA + c * 8);
    }
    #pragma unroll
    for (int i = 0; i < BCH; i++) {
      int c = i * 256 + tid;
      GLOAD_LDS16(Bt + (rowB0 + (c >> 3)) * K + kt * 64 + (c & 7) * 8, lsB + c * 8);
    }
    __syncthreads();   // compiler emits vmcnt(0) drain here
    #pragma unroll
    for (int s = 0; s < 2; s++) {
      f16x8 af[4], bf[NF];
      #pragma unroll
      for (int mf = 0; mf < 4; mf++)
        af[mf] = *(const f16x8*)(lsA + (wm * 64 + mf * 16 + lr) * 64 + s * 32 + lh * 8);
      #pragma unroll
      for (int nf = 0; nf < NF; nf++)
        bf[nf] = *(const f16x8*)(lsB + (wn * (BN / 2) + nf * 16 + lr) * 64 + s * 32 + lh * 8);
      #pragma unroll
      for (int mf = 0; mf < 4; mf++)
        #pragma unroll
        for (int nf = 0; nf < NF; nf++)
          acc[mf][nf] = MFMA16(af[mf], bf[nf], acc[mf][nf]);
    }
  }

  #pragma unroll
  for (int mf = 0; mf < 4; mf++) {
    #pragma unroll
    for (int nf = 0; nf < NF; nf++) {
      const int token = bm * BM + wm * 64 + mf * 16 + lh * 4;
      const int ch = bn * BN + wn * (BN / 2) + nf * 16 + lr;
      #pragma unroll
      for (int r = 0; r < 4; r++) {
        float v = acc[mf][nf][r];
        size_t idx = (size_t)(token + r) * N + ch;
        if constexpr (MODE == 0) {
          Oz[idx] = (f16)v;
        } else if constexpr (MODE == 1) {
          xio[idx] += v;
        } else if constexpr (MODE == 2) {
          v += bias[ch];
          Oz[idx] = (f16)fmaxf(v, 0.f);
        } else {
          xio[idx] += v + bias[ch];
        }
      }
    }
  }
}

// ---------------------------------------------------------------- V transpose
__global__ __launch_bounds__(256) void vtrans_k(
    const f16* __restrict__ v, f16* __restrict__ vt)
{
  __shared__ f16 t[64][80];
  const int tid = threadIdx.x;
  const int st = blockIdx.x, bh = blockIdx.y;
  const int b = bh >> 3, h = bh & 7;
  #pragma unroll
  for (int i = 0; i < 2; i++) {
    int c = i * 256 + tid; int s = c >> 3, sl = c & 7;
    *(int4*)&t[s][sl * 8] =
        *(const int4*)(v + (size_t)(b * Sx + st * 64 + s) * Dm + h * 64 + sl * 8);
  }
  __syncthreads();
  #pragma unroll
  for (int i = 0; i < 2; i++) {
    int c = i * 256 + tid; int dv = c >> 3, sl = c & 7;
    f16 tmp[8];
    #pragma unroll
    for (int j = 0; j < 8; j++) tmp[j] = t[sl * 8 + j][dv];
    *(int4*)(vt + (size_t)(bh * 64 + dv) * Sx + st * 64 + sl * 8) = *(const int4*)tmp;
  }
}

// ---------------------------------------------------------------- attention
// Transposed flash attention; 4 waves/block, 128 queries/block.
// LDS tiles stored XOR-swizzled (16B granule ^= row&7) via pre-swizzled
// global source addresses + linear global_load_lds dest; reads apply the
// same XOR -> bank-conflict-free b128/b64 reads.
__global__ __launch_bounds__(256) void attn_k(
    const f16* __restrict__ q, const f16* __restrict__ kk,
    const f16* __restrict__ vt, const int* __restrict__ src,
    f16* __restrict__ out)
{
  __shared__ f16 lsK[2][64 * 64];
  __shared__ f16 lsV[2][64 * 64];
  const int tid = threadIdx.x;
  const int l = tid & 63, w = tid >> 6;
  const int lr = l & 15, lh = l >> 4;
  const int qt = blockIdx.x;     // 0..15
  const int bh = blockIdx.y;     // 0..15
  const int b = bh >> 3, h = bh & 7;

  // Q fragments, pre-scaled by 1/sqrt(DK)=0.125
  f16x8 qf[2][2];
  #pragma unroll
  for (int s = 0; s < 2; s++)
    #pragma unroll
    for (int j = 0; j < 2; j++) {
      size_t row = (size_t)(b * Sx + qt * 128 + w * 32 + j * 16 + lr);
      f16x8 t = *(const f16x8*)(q + row * Dm + h * 64 + s * 32 + lh * 8);
      qf[s][j] = t * (_Float16)0.125f;
    }

  f32x4 oacc[4][2] = {};
  float mrun[2] = {-1e30f, -1e30f};
  float lrun[2] = {0.f, 0.f};

  // stage tile kt into buffer pb; global source column-granule pre-swizzled
  auto stage = [&](int kt, int pb) {
    #pragma unroll
    for (int i = 0; i < 2; i++) {
      int c = i * 256 + tid, r = c >> 3, g = c & 7, gs = g ^ (r & 7);
      GLOAD_LDS16(kk + (size_t)(b * Sx + kt * 64 + r) * Dm + h * 64 + gs * 8,
                  &lsK[pb][c * 8]);
      GLOAD_LDS16(vt + (size_t)(bh * 64 + r) * Sx + kt * 64 + gs * 8,
                  &lsV[pb][c * 8]);
    }
  };
  stage(0, 0);

  for (int kt = 0; kt < 32; ++kt) {
    const int cur = kt & 1;
    __syncthreads();               // vmcnt(0) drain: buf[cur] ready
    if (kt < 31) stage(kt + 1, cur ^ 1);

    // ---- S^T = K @ Q^T
    f32x4 sacc[4][2] = {};
    #pragma unroll
    for (int s = 0; s < 2; s++) {
      const int gk = (s * 4 + lh) ^ (lr & 7);
      #pragma unroll
      for (int kf = 0; kf < 4; kf++) {
        f16x8 a = *(const f16x8*)(&lsK[cur][(kf * 16 + lr) * 64 + gk * 8]);
        sacc[kf][0] = MFMA16(a, qf[s][0], sacc[kf][0]);
        sacc[kf][1] = MFMA16(a, qf[s][1], sacc[kf][1]);
      }
    }
    // ---- key padding mask (key = kt*64 + kf*16 + lh*4 + r)
    #pragma unroll
    for (int kf = 0; kf < 4; kf++) {
      int4 m4 = *(const int4*)(src + b * Sx + kt * 64 + kf * 16 + lh * 4);
      const int* mp = (const int*)&m4;
      #pragma unroll
      for (int r = 0; r < 4; r++)
        if (mp[r] == 0) { sacc[kf][0][r] = -1e30f; sacc[kf][1][r] = -1e30f; }
    }
    // ---- online softmax; lane owns query col = lane&15
    f16x8 pa[2][2];
    #pragma unroll
    for (int j = 0; j < 2; j++) {
      float mx = -1e30f;
      #pragma unroll
      for (int kf = 0; kf < 4; kf++)
        #pragma unroll
        for (int r = 0; r < 4; r++) mx = fmaxf(mx, sacc[kf][j][r]);
      mx = fmaxf(mx, __shfl_xor(mx, 16));
      mx = fmaxf(mx, __shfl_xor(mx, 32));
      const float mnew = fmaxf(mrun[j], mx);
      const float resc = __expf(mrun[j] - mnew);
      float ps = 0.f;
      #pragma unroll
      for (int kf = 0; kf < 4; kf++)
        #pragma unroll
        for (int r = 0; r < 4; r++) {
          float p = __expf(sacc[kf][j][r] - mnew);
          sacc[kf][j][r] = p;
          ps += p;
        }
      ps += __shfl_xor(ps, 16);
      ps += __shfl_xor(ps, 32);
      lrun[j] = lrun[j] * resc + ps;
      mrun[j] = mnew;
      #pragma unroll
      for (int mf = 0; mf < 4; mf++) oacc[mf][j] *= resc;
      // pack P^T: element jj -> key = 32s + 16*(jj>>2) + lh*4 + (jj&3)
      #pragma unroll
      for (int s = 0; s < 2; s++)
        #pragma unroll
        for (int jj = 0; jj < 8; jj++)
          pa[s][j][jj] = (f16)sacc[2 * s + (jj >> 2)][j][jj & 3];
    }
    // ---- O^T += V^T @ P^T (same key bijection; swizzled b64 reads)
    #pragma unroll
    for (int s = 0; s < 2; s++) {
      const int g0 = (s * 4 + (lh >> 1)) ^ (lr & 7);
      const int g1 = ((s * 4 + (lh >> 1)) + 2) ^ (lr & 7);
      #pragma unroll
      for (int mf = 0; mf < 4; mf++) {
        union { f16x8 v8; f16x4 v4[2]; } u;
        const f16* vbase = &lsV[cur][(mf * 16 + lr) * 64];
        u.v4[0] = *(const f16x4*)(vbase + g0 * 8 + (lh & 1) * 4);
        u.v4[1] = *(const f16x4*)(vbase + g1 * 8 + (lh & 1) * 4);
        oacc[mf][0] = MFMA16(u.v8, pa[s][0], oacc[mf][0]);
        oacc[mf][1] = MFMA16(u.v8, pa[s][1], oacc[mf][1]);
      }
    }
  }

  // ---- write O: lane's q = lane&15; dv = mf*16 + lh*4 + r
  #pragma unroll
  for (int j = 0; j < 2; j++) {
    const float inv = 1.f / lrun[j];
    size_t row = (size_t)(b * Sx + qt * 128 + w * 32 + j * 16 + lr);
    #pragma unroll
    for (int mf = 0; mf < 4; mf++) {
      f16x4 o;
      #pragma unroll
      for (int r = 0; r < 4; r++) o[r] = (f16)(oacc[mf][j][r] * inv);
      *(f16x4*)(out + row * Dm + h * 64 + mf * 16 + lh * 4) = o;
    }
  }
}

// ---------------------------------------------------------------- launch
extern "C" void kernel_launch(void* const* d_in, const int* in_sizes, int n_in,
                              void* d_out, int out_size, void* d_ws, size_t ws_size,
                              hipStream_t stream)
{
  (void)in_sizes; (void)n_in; (void)out_size; (void)ws_size;
  const int*   src  = (const int*)d_in[0];
  const float* emb  = (const float*)d_in[1];
  const float* pe   = (const float*)d_in[2];
  const float* WQ   = (const float*)d_in[3];
  const float* WK   = (const float*)d_in[4];
  const float* WV   = (const float*)d_in[5];
  const float* WO   = (const float*)d_in[6];
  const float* W1   = (const float*)d_in[7];
  const float* b1   = (const float*)d_in[8];
  const float* W2   = (const float*)d_in[9];
  const float* b2   = (const float*)d_in[10];
  const float* ln1s = (const float*)d_in[11];
  const float* ln1b = (const float*)d_in[12];
  const float* ln2s = (const float*)d_in[13];
  const float* ln2b = (const float*)d_in[14];
  const float* fns  = (const float*)d_in[15];
  const float* fnb  = (const float*)d_in[16];

  char* ws = (char*)d_ws;
  const size_t DD = (size_t)Dm * Dm;
  const size_t DF = (size_t)Dm * DFFm;
  f16* wtQ = (f16*)(ws);
  f16* wtK = wtQ + Lc * DD;
  f16* wtV = wtK + Lc * DD;
  f16* wtO = wtV + Lc * DD;
  f16* wt1 = wtO + Lc * DD;
  f16* wt2 = wt1 + Lc * DF;
  float* x  = (float*)(wt2 + Lc * DF);
  f16* hbuf = (f16*)(x + (size_t)NTOK * Dm);
  f16* qb   = hbuf + (size_t)NTOK * Dm;
  f16* kb   = qb + (size_t)NTOK * Dm;
  f16* vraw = kb + (size_t)NTOK * Dm;
  f16* vtb  = vraw + (size_t)NTOK * Dm;
  f16* attn = vtb + (size_t)NTOK * Dm;
  f16* ff   = attn + (size_t)NTOK * Dm;

  const dim3 tb(32, 8);
  transpose_cvt<<<dim3(16, 16, Lc), tb, 0, stream>>>(WQ, wtQ, Dm, Dm);
  transpose_cvt<<<dim3(16, 16, Lc), tb, 0, stream>>>(WK, wtK, Dm, Dm);
  transpose_cvt<<<dim3(16, 16, Lc), tb, 0, stream>>>(WV, wtV, Dm, Dm);
  transpose_cvt<<<dim3(16, 16, Lc), tb, 0, stream>>>(WO, wtO, Dm, Dm);
  transpose_cvt<<<dim3(64, 16, Lc), tb, 0, stream>>>(W1, wt1, Dm, DFFm);
  transpose_cvt<<<dim3(16, 64, Lc), tb, 0, stream>>>(W2, wt2, DFFm, Dm);

  embed_k<<<1024, 256, 0, stream>>>(src, emb, pe, x);

  for (int l = 0; l < Lc; l++) {
    const f16* wq = wtQ + (size_t)l * DD;
    const f16* wk = wtK + (size_t)l * DD;
    const f16* wv = wtV + (size_t)l * DD;
    const f16* wo = wtO + (size_t)l * DD;
    const f16* w1 = wt1 + (size_t)l * DF;
    const f16* w2 = wt2 + (size_t)l * DF;

    ln_k<f16><<<1024, 256, 0, stream>>>(x, ln1s + l * Dm, ln1b + l * Dm, hbuf);
    gemm_k<64, 0><<<dim3(32, 8, 3), 256, 0, stream>>>(
        hbuf, wq, wk, wv, qb, kb, vraw, nullptr, nullptr, Dm, Dm);
    vtrans_k<<<dim3(32, 16), 256, 0, stream>>>(vraw, vtb);
    attn_k<<<dim3(16, 16), 256, 0, stream>>>(qb, kb, vtb, src, attn);
    gemm_k<64, 1><<<dim3(32, 8, 1), 256, 0, stream>>>(
        attn, wo, wo, wo, nullptr, nullptr, nullptr, x, nullptr, Dm, Dm);
    ln_k<f16><<<1024, 256, 0, stream>>>(x, ln2s + l * Dm, ln2b + l * Dm, hbuf);
    gemm_k<128, 2><<<dim3(32, 16, 1), 256, 0, stream>>>(
        hbuf, w1, w1, w1, ff, ff, ff, nullptr, b1 + (size_t)l * DFFm, DFFm, Dm);
    gemm_k<64, 3><<<dim3(32, 8, 1), 256, 0, stream>>>(
        ff, w2, w2, w2, nullptr, nullptr, nullptr, x, b2 + (size_t)l * Dm, Dm, DFFm);
  }

  ln_k<float><<<1024, 256, 0, stream>>>(x, fns, fnb, (float*)d_out);
}

// Round 3
// 875.196 us; speedup vs baseline: 2.4773x; 1.1663x over previous
//
#include <hip/hip_runtime.h>

// ---------------------------------------------------------------------------
// Transformer encoder (B=2, S=2048, D=512, H=8, DK=64, DFF=2048, L=6), fp16
// MFMA compute, f32 residual stream.
// R3: attn 2 waves/SIMD (16 q/wave, 512 blocks) + XCD swizzle + exp2-domain
// softmax + defer-max + setprio; GEMMs get XCD swizzle, WO/W2 at BN=32 for
// 2 blocks/CU.
// ---------------------------------------------------------------------------

typedef _Float16 f16;
typedef _Float16 f16x8 __attribute__((ext_vector_type(8)));
typedef _Float16 f16x4 __attribute__((ext_vector_type(4)));
typedef float    f32x4 __attribute__((ext_vector_type(4)));

#define MFMA16(a, b, c) __builtin_amdgcn_mfma_f32_16x16x32_f16((a), (b), (c), 0, 0, 0)
#define GLOAD_LDS16(GP, LP)                                        \
  __builtin_amdgcn_global_load_lds(                                \
      (const __attribute__((address_space(1))) void*)(GP),         \
      (__attribute__((address_space(3))) void*)(LP), 16, 0, 0)

__device__ inline float fast_exp2(float x) {
#if __has_builtin(__builtin_amdgcn_exp2f)
  return __builtin_amdgcn_exp2f(x);
#else
  return exp2f(x);
#endif
}

static constexpr int Dm  = 512;
static constexpr int Sx  = 2048;
static constexpr int NTOK = 4096;   // B*S
static constexpr int DFFm = 2048;
static constexpr int Lc  = 6;

// ---------------------------------------------------------------- transpose+cvt
__global__ __launch_bounds__(256) void transpose_cvt(
    const float* __restrict__ in, f16* __restrict__ out, int R, int C)
{
  __shared__ float t[32][33];
  const int z = blockIdx.z;
  const float* src = in + (size_t)z * R * C;
  f16* dst = out + (size_t)z * R * C;
  const int r0 = blockIdx.y * 32, c0 = blockIdx.x * 32;
  const int tx = threadIdx.x, ty = threadIdx.y;
  #pragma unroll
  for (int i = 0; i < 4; i++)
    t[ty + i * 8][tx] = src[(size_t)(r0 + ty + i * 8) * C + c0 + tx];
  __syncthreads();
  #pragma unroll
  for (int i = 0; i < 4; i++)
    dst[(size_t)(c0 + ty + i * 8) * R + r0 + tx] = (f16)t[tx][ty + i * 8];
}

// ---------------------------------------------------------------- embedding
__global__ __launch_bounds__(256) void embed_k(
    const int* __restrict__ src, const float* __restrict__ emb,
    const float* __restrict__ pe, float* __restrict__ x)
{
  const int gid = blockIdx.x * 256 + threadIdx.x;
  const int token = gid >> 6;
  const int d0 = (gid & 63) << 3;
  const int s = token & (Sx - 1);
  const int tk = src[token];
  const float* e = emb + (size_t)tk * Dm + d0;
  const float* p = pe + (size_t)s * Dm + d0;
  float* o = x + (size_t)token * Dm + d0;
  const float SC = 22.627416997969522f;  // sqrt(512)
  #pragma unroll
  for (int j = 0; j < 8; j++) o[j] = e[j] * SC + p[j];
}

// ---------------------------------------------------------------- layernorm
template <typename OUT>
__global__ __launch_bounds__(256) void ln_k(
    const float* __restrict__ x, const float* __restrict__ sc,
    const float* __restrict__ bi, OUT* __restrict__ out)
{
  const int row = blockIdx.x * 4 + (threadIdx.x >> 6);
  const int l = threadIdx.x & 63;
  const float* px = x + (size_t)row * Dm + l * 8;
  float v[8];
  *(float4*)&v[0] = *(const float4*)px;
  *(float4*)&v[4] = *(const float4*)(px + 4);
  float s = 0.f;
  #pragma unroll
  for (int j = 0; j < 8; j++) s += v[j];
  #pragma unroll
  for (int m = 1; m < 64; m <<= 1) s += __shfl_xor(s, m);
  const float mu = s * (1.0f / 512.0f);
  float qv = 0.f;
  #pragma unroll
  for (int j = 0; j < 8; j++) { float d = v[j] - mu; qv += d * d; }
  #pragma unroll
  for (int m = 1; m < 64; m <<= 1) qv += __shfl_xor(qv, m);
  const float inv = rsqrtf(qv * (1.0f / 512.0f) + 1e-5f);
  float scv[8], biv[8];
  *(float4*)&scv[0] = *(const float4*)(sc + l * 8);
  *(float4*)&scv[4] = *(const float4*)(sc + l * 8 + 4);
  *(float4*)&biv[0] = *(const float4*)(bi + l * 8);
  *(float4*)&biv[4] = *(const float4*)(bi + l * 8 + 4);
  if constexpr (sizeof(OUT) == 2) {
    f16x8 o;
    #pragma unroll
    for (int j = 0; j < 8; j++) o[j] = (f16)((v[j] - mu) * inv * scv[j] + biv[j]);
    *(f16x8*)((f16*)out + (size_t)row * Dm + l * 8) = o;
  } else {
    float o[8];
    #pragma unroll
    for (int j = 0; j < 8; j++) o[j] = (v[j] - mu) * inv * scv[j] + biv[j];
    float* po = (float*)out + (size_t)row * Dm + l * 8;
    *(float4*)po = *(float4*)&o[0];
    *(float4*)(po + 4) = *(float4*)&o[4];
  }
}

// ---------------------------------------------------------------- GEMM
// C[4096][N] = A[4096][K] * Bt[N][K]^T; m97 structure + XCD swizzle (1D grid).
// MODE 0: out=f16 (QKV, z in {0,1,2}) | 1: xio+=acc | 2: relu(acc+bias)->f16
// MODE 3: xio += acc + bias
template <int BN, int MODE, int N, int K>
__global__ __launch_bounds__(256) void gemm_k(
    const f16* __restrict__ A,
    const f16* __restrict__ B0, const f16* __restrict__ B1, const f16* __restrict__ B2,
    f16* __restrict__ O0, f16* __restrict__ O1, f16* __restrict__ O2,
    float* __restrict__ xio, const float* __restrict__ bias)
{
  constexpr int BM = 128;
  constexpr int NF = (BN >= 32) ? (BN / 32) : 1;
  constexpr int NBM = NTOK / BM;            // 32
  constexpr int NBN = N / BN;
  constexpr int NZ = (MODE == 0) ? 3 : 1;
  constexpr int NB = NBM * NBN * NZ;        // multiple of 8
  __shared__ f16 lsA[BM * 64];
  __shared__ f16 lsB[BN * 64];
  const int tid = threadIdx.x;
  const int l = tid & 63, w = tid >> 6;
  const int lr = l & 15, lh = l >> 4;
  const int wm = w >> 1, wn = w & 1;
  // XCD-aware bijective swizzle: same-XCD blocks get contiguous (z,bm) stripe
  const int bid = blockIdx.x;
  const int nid = (bid & 7) * (NB / 8) + (bid >> 3);
  const int z = nid / (NBM * NBN);
  const int rr = nid % (NBM * NBN);
  const int bm = rr / NBN, bn = rr % NBN;
  const f16* Bt = (z == 0) ? B0 : ((z == 1) ? B1 : B2);
  f16* Oz = (z == 0) ? O0 : ((z == 1) ? O1 : O2);

  constexpr int ACH = (BM * 64) / (256 * 8);   // 4
  constexpr int BCH = (BN * 64) / (256 * 8);   // 1, 2 or 4
  const size_t rowA0 = (size_t)bm * BM;
  const size_t rowB0 = (size_t)bn * BN;

  f32x4 acc[4][NF] = {};
  constexpr int NT = K >> 6;
  for (int kt = 0; kt < NT; ++kt) {
    __syncthreads();
    #pragma unroll
    for (int i = 0; i < ACH; i++) {
      int c = i * 256 + tid;
      GLOAD_LDS16(A + (rowA0 + (c >> 3)) * K + kt * 64 + (c & 7) * 8, lsA + c * 8);
    }
    #pragma unroll
    for (int i = 0; i < BCH; i++) {
      int c = i * 256 + tid;
      GLOAD_LDS16(Bt + (rowB0 + (c >> 3)) * K + kt * 64 + (c & 7) * 8, lsB + c * 8);
    }
    __syncthreads();
    #pragma unroll
    for (int s = 0; s < 2; s++) {
      f16x8 af[4], bf[NF];
      #pragma unroll
      for (int mf = 0; mf < 4; mf++)
        af[mf] = *(const f16x8*)(lsA + (wm * 64 + mf * 16 + lr) * 64 + s * 32 + lh * 8);
      #pragma unroll
      for (int nf = 0; nf < NF; nf++)
        bf[nf] = *(const f16x8*)(lsB + (wn * (BN / 2) + nf * 16 + lr) * 64 + s * 32 + lh * 8);
      #pragma unroll
      for (int mf = 0; mf < 4; mf++)
        #pragma unroll
        for (int nf = 0; nf < NF; nf++)
          acc[mf][nf] = MFMA16(af[mf], bf[nf], acc[mf][nf]);
    }
  }

  #pragma unroll
  for (int mf = 0; mf < 4; mf++) {
    #pragma unroll
    for (int nf = 0; nf < NF; nf++) {
      const int token = bm * BM + wm * 64 + mf * 16 + lh * 4;
      const int ch = bn * BN + wn * (BN / 2) + nf * 16 + lr;
      #pragma unroll
      for (int r = 0; r < 4; r++) {
        float v = acc[mf][nf][r];
        size_t idx = (size_t)(token + r) * N + ch;
        if constexpr (MODE == 0) {
          Oz[idx] = (f16)v;
        } else if constexpr (MODE == 1) {
          xio[idx] += v;
        } else if constexpr (MODE == 2) {
          v += bias[ch];
          Oz[idx] = (f16)fmaxf(v, 0.f);
        } else {
          xio[idx] += v + bias[ch];
        }
      }
    }
  }
}

// ---------------------------------------------------------------- V transpose
__global__ __launch_bounds__(256) void vtrans_k(
    const f16* __restrict__ v, f16* __restrict__ vt)
{
  __shared__ f16 t[64][80];
  const int tid = threadIdx.x;
  const int st = blockIdx.x, bh = blockIdx.y;
  const int b = bh >> 3, h = bh & 7;
  #pragma unroll
  for (int i = 0; i < 2; i++) {
    int c = i * 256 + tid; int s = c >> 3, sl = c & 7;
    *(int4*)&t[s][sl * 8] =
        *(const int4*)(v + (size_t)(b * Sx + st * 64 + s) * Dm + h * 64 + sl * 8);
  }
  __syncthreads();
  #pragma unroll
  for (int i = 0; i < 2; i++) {
    int c = i * 256 + tid; int dv = c >> 3, sl = c & 7;
    f16 tmp[8];
    #pragma unroll
    for (int j = 0; j < 8; j++) tmp[j] = t[sl * 8 + j][dv];
    *(int4*)(vt + (size_t)(bh * 64 + dv) * Sx + st * 64 + sl * 8) = *(const int4*)tmp;
  }
}

// ---------------------------------------------------------------- attention
// Transposed flash attention, exp2 domain. 4 waves/block, 16 queries/wave,
// 64 queries/block, grid 512 (XCD-swizzled: same-bh contiguous on one XCD).
// K/V LDS XOR-swizzled via pre-swizzled global source (linear gload_lds dest).
__global__ __launch_bounds__(256) void attn_k(
    const f16* __restrict__ q, const f16* __restrict__ kk,
    const f16* __restrict__ vt, const int* __restrict__ src,
    f16* __restrict__ out)
{
  __shared__ f16 lsK[2][64 * 64];
  __shared__ f16 lsV[2][64 * 64];
  const int tid = threadIdx.x;
  const int l = tid & 63, w = tid >> 6;
  const int lr = l & 15, lh = l >> 4;
  const int bid = blockIdx.x;
  const int nid = ((bid & 7) << 6) + (bid >> 3);   // NB=512, chunk 64
  const int bh = nid >> 5;                          // 0..15 (2 per XCD)
  const int qt = nid & 31;                          // 0..31
  const int b = bh >> 3, h = bh & 7;

  // Q frag, scaled by (1/sqrt(64)) * log2(e) -> scores in log2 domain
  const _Float16 QS = (_Float16)0.18033688f;
  f16x8 qf[2];
  #pragma unroll
  for (int s = 0; s < 2; s++) {
    size_t row = (size_t)(b * Sx + qt * 64 + w * 16 + lr);
    f16x8 t = *(const f16x8*)(q + row * Dm + h * 64 + s * 32 + lh * 8);
    qf[s] = t * QS;
  }

  f32x4 oacc[4] = {};
  float mrun = -1e30f;
  float lrun = 0.f;

  auto stage = [&](int kt, int pb) {
    #pragma unroll
    for (int i = 0; i < 2; i++) {
      int c = i * 256 + tid, r = c >> 3, g = c & 7, gs = g ^ (r & 7);
      GLOAD_LDS16(kk + (size_t)(b * Sx + kt * 64 + r) * Dm + h * 64 + gs * 8,
                  &lsK[pb][c * 8]);
      GLOAD_LDS16(vt + (size_t)(bh * 64 + r) * Sx + kt * 64 + gs * 8,
                  &lsV[pb][c * 8]);
    }
  };
  stage(0, 0);

  for (int kt = 0; kt < 32; ++kt) {
    const int cur = kt & 1;
    __syncthreads();               // vmcnt(0) drain: buf[cur] ready
    if (kt < 31) stage(kt + 1, cur ^ 1);

    // ---- S^T = K @ Q^T (log2 domain)
    f32x4 sacc[4] = {};
    __builtin_amdgcn_s_setprio(1);
    #pragma unroll
    for (int s = 0; s < 2; s++) {
      const int gk = (s * 4 + lh) ^ (lr & 7);
      #pragma unroll
      for (int kf = 0; kf < 4; kf++) {
        f16x8 a = *(const f16x8*)(&lsK[cur][(kf * 16 + lr) * 64 + gk * 8]);
        sacc[kf] = MFMA16(a, qf[s], sacc[kf]);
      }
    }
    __builtin_amdgcn_s_setprio(0);

    // ---- key padding mask (key = kt*64 + kf*16 + lh*4 + r)
    #pragma unroll
    for (int kf = 0; kf < 4; kf++) {
      int4 m4 = *(const int4*)(src + b * Sx + kt * 64 + kf * 16 + lh * 4);
      const int* mp = (const int*)&m4;
      #pragma unroll
      for (int r = 0; r < 4; r++)
        if (mp[r] == 0) sacc[kf][r] = -3.0e38f;
    }

    // ---- online softmax (exp2); lane owns query col = lane&15
    float pmax = -3.0e38f;
    #pragma unroll
    for (int kf = 0; kf < 4; kf++)
      #pragma unroll
      for (int r = 0; r < 4; r++) pmax = fmaxf(pmax, sacc[kf][r]);
    pmax = fmaxf(pmax, __shfl_xor(pmax, 16));
    pmax = fmaxf(pmax, __shfl_xor(pmax, 32));
    if (!__all(pmax - mrun <= 8.0f)) {       // defer-max (T13, THR=8 log2)
      const float mnew = fmaxf(mrun, pmax);
      const float rs = fast_exp2(mrun - mnew);
      lrun *= rs;
      #pragma unroll
      for (int mf = 0; mf < 4; mf++) oacc[mf] *= rs;
      mrun = mnew;
    }
    float ps = 0.f;
    f16x8 pa[2];
    #pragma unroll
    for (int kf = 0; kf < 4; kf++)
      #pragma unroll
      for (int r = 0; r < 4; r++) {
        float p = fast_exp2(sacc[kf][r] - mrun);
        sacc[kf][r] = p;
        ps += p;
      }
    ps += __shfl_xor(ps, 16);
    ps += __shfl_xor(ps, 32);
    lrun += ps;
    // pack P^T: element jj -> key = 32s + 16*(jj>>2) + lh*4 + (jj&3)
    #pragma unroll
    for (int s = 0; s < 2; s++)
      #pragma unroll
      for (int jj = 0; jj < 8; jj++)
        pa[s][jj] = (f16)sacc[2 * s + (jj >> 2)][jj & 3];

    // ---- O^T += V^T @ P^T
    __builtin_amdgcn_s_setprio(1);
    #pragma unroll
    for (int s = 0; s < 2; s++) {
      const int g0 = (s * 4 + (lh >> 1)) ^ (lr & 7);
      const int g1 = ((s * 4 + (lh >> 1)) + 2) ^ (lr & 7);
      #pragma unroll
      for (int mf = 0; mf < 4; mf++) {
        union { f16x8 v8; f16x4 v4[2]; } u;
        const f16* vbase = &lsV[cur][(mf * 16 + lr) * 64];
        u.v4[0] = *(const f16x4*)(vbase + g0 * 8 + (lh & 1) * 4);
        u.v4[1] = *(const f16x4*)(vbase + g1 * 8 + (lh & 1) * 4);
        oacc[mf] = MFMA16(u.v8, pa[s], oacc[mf]);
      }
    }
    __builtin_amdgcn_s_setprio(0);
  }

  // ---- write O: lane's q = lane&15; dv = mf*16 + lh*4 + r
  const float inv = 1.f / lrun;
  size_t row = (size_t)(b * Sx + qt * 64 + w * 16 + lr);
  #pragma unroll
  for (int mf = 0; mf < 4; mf++) {
    f16x4 o;
    #pragma unroll
    for (int r = 0; r < 4; r++) o[r] = (f16)(oacc[mf][r] * inv);
    *(f16x4*)(out + row * Dm + h * 64 + mf * 16 + lh * 4) = o;
  }
}

// ---------------------------------------------------------------- launch
extern "C" void kernel_launch(void* const* d_in, const int* in_sizes, int n_in,
                              void* d_out, int out_size, void* d_ws, size_t ws_size,
                              hipStream_t stream)
{
  (void)in_sizes; (void)n_in; (void)out_size; (void)ws_size;
  const int*   src  = (const int*)d_in[0];
  const float* emb  = (const float*)d_in[1];
  const float* pe   = (const float*)d_in[2];
  const float* WQ   = (const float*)d_in[3];
  const float* WK   = (const float*)d_in[4];
  const float* WV   = (const float*)d_in[5];
  const float* WO   = (const float*)d_in[6];
  const float* W1   = (const float*)d_in[7];
  const float* b1   = (const float*)d_in[8];
  const float* W2   = (const float*)d_in[9];
  const float* b2   = (const float*)d_in[10];
  const float* ln1s = (const float*)d_in[11];
  const float* ln1b = (const float*)d_in[12];
  const float* ln2s = (const float*)d_in[13];
  const float* ln2b = (const float*)d_in[14];
  const float* fns  = (const float*)d_in[15];
  const float* fnb  = (const float*)d_in[16];

  char* ws = (char*)d_ws;
  const size_t DD = (size_t)Dm * Dm;
  const size_t DF = (size_t)Dm * DFFm;
  f16* wtQ = (f16*)(ws);
  f16* wtK = wtQ + Lc * DD;
  f16* wtV = wtK + Lc * DD;
  f16* wtO = wtV + Lc * DD;
  f16* wt1 = wtO + Lc * DD;
  f16* wt2 = wt1 + Lc * DF;
  float* x  = (float*)(wt2 + Lc * DF);
  f16* hbuf = (f16*)(x + (size_t)NTOK * Dm);
  f16* qb   = hbuf + (size_t)NTOK * Dm;
  f16* kb   = qb + (size_t)NTOK * Dm;
  f16* vraw = kb + (size_t)NTOK * Dm;
  f16* vtb  = vraw + (size_t)NTOK * Dm;
  f16* attn = vtb + (size_t)NTOK * Dm;
  f16* ff   = attn + (size_t)NTOK * Dm;

  const dim3 tb(32, 8);
  transpose_cvt<<<dim3(16, 16, Lc), tb, 0, stream>>>(WQ, wtQ, Dm, Dm);
  transpose_cvt<<<dim3(16, 16, Lc), tb, 0, stream>>>(WK, wtK, Dm, Dm);
  transpose_cvt<<<dim3(16, 16, Lc), tb, 0, stream>>>(WV, wtV, Dm, Dm);
  transpose_cvt<<<dim3(16, 16, Lc), tb, 0, stream>>>(WO, wtO, Dm, Dm);
  transpose_cvt<<<dim3(64, 16, Lc), tb, 0, stream>>>(W1, wt1, Dm, DFFm);
  transpose_cvt<<<dim3(16, 64, Lc), tb, 0, stream>>>(W2, wt2, DFFm, Dm);

  embed_k<<<1024, 256, 0, stream>>>(src, emb, pe, x);

  for (int l = 0; l < Lc; l++) {
    const f16* wq = wtQ + (size_t)l * DD;
    const f16* wk = wtK + (size_t)l * DD;
    const f16* wv = wtV + (size_t)l * DD;
    const f16* wo = wtO + (size_t)l * DD;
    const f16* w1 = wt1 + (size_t)l * DF;
    const f16* w2 = wt2 + (size_t)l * DF;

    ln_k<f16><<<1024, 256, 0, stream>>>(x, ln1s + l * Dm, ln1b + l * Dm, hbuf);
    gemm_k<64, 0, 512, 512><<<768, 256, 0, stream>>>(
        hbuf, wq, wk, wv, qb, kb, vraw, nullptr, nullptr);
    vtrans_k<<<dim3(32, 16), 256, 0, stream>>>(vraw, vtb);
    attn_k<<<512, 256, 0, stream>>>(qb, kb, vtb, src, attn);
    gemm_k<32, 1, 512, 512><<<512, 256, 0, stream>>>(
        attn, wo, wo, wo, nullptr, nullptr, nullptr, x, nullptr);
    ln_k<f16><<<1024, 256, 0, stream>>>(x, ln2s + l * Dm, ln2b + l * Dm, hbuf);
    gemm_k<128, 2, 2048, 512><<<512, 256, 0, stream>>>(
        hbuf, w1, w1, w1, ff, ff, ff, nullptr, b1 + (size_t)l * DFFm);
    gemm_k<32, 3, 512, 2048><<<512, 256, 0, stream>>>(
        ff, w2, w2, w2, nullptr, nullptr, nullptr, x, b2 + (size_t)l * Dm);
  }

  ln_k<float><<<1024, 256, 0, stream>>>(x, fns, fnb, (float*)d_out);
}

// Round 4
// 742.720 us; speedup vs baseline: 2.9191x; 1.1784x over previous
//
#include <hip/hip_runtime.h>

// ---------------------------------------------------------------------------
// Transformer encoder (B=2, S=2048, D=512, H=8, DK=64, DFF=2048, L=6), fp16
// MFMA compute, f32 residual stream.
// R4: attn flash split-K (8 waves, 2 key-groups, LDS merge) -> 4 waves/SIMD;
// mask folded into MFMA C-init (zero VALU); V-transpose fused into QKV GEMM
// epilogue (vtrans kernel removed).
// ---------------------------------------------------------------------------

typedef _Float16 f16;
typedef _Float16 f16x8 __attribute__((ext_vector_type(8)));
typedef _Float16 f16x4 __attribute__((ext_vector_type(4)));
typedef float    f32x4 __attribute__((ext_vector_type(4)));

#define MFMA16(a, b, c) __builtin_amdgcn_mfma_f32_16x16x32_f16((a), (b), (c), 0, 0, 0)
#define GLOAD_LDS16(GP, LP)                                        \
  __builtin_amdgcn_global_load_lds(                                \
      (const __attribute__((address_space(1))) void*)(GP),         \
      (__attribute__((address_space(3))) void*)(LP), 16, 0, 0)

__device__ inline float fast_exp2(float x) {
#if __has_builtin(__builtin_amdgcn_exp2f)
  return __builtin_amdgcn_exp2f(x);
#else
  return exp2f(x);
#endif
}

static constexpr int Dm  = 512;
static constexpr int Sx  = 2048;
static constexpr int NTOK = 4096;   // B*S
static constexpr int DFFm = 2048;
static constexpr int Lc  = 6;

// ---------------------------------------------------------------- transpose+cvt
__global__ __launch_bounds__(256) void transpose_cvt(
    const float* __restrict__ in, f16* __restrict__ out, int R, int C)
{
  __shared__ float t[32][33];
  const int z = blockIdx.z;
  const float* src = in + (size_t)z * R * C;
  f16* dst = out + (size_t)z * R * C;
  const int r0 = blockIdx.y * 32, c0 = blockIdx.x * 32;
  const int tx = threadIdx.x, ty = threadIdx.y;
  #pragma unroll
  for (int i = 0; i < 4; i++)
    t[ty + i * 8][tx] = src[(size_t)(r0 + ty + i * 8) * C + c0 + tx];
  __syncthreads();
  #pragma unroll
  for (int i = 0; i < 4; i++)
    dst[(size_t)(c0 + ty + i * 8) * R + r0 + tx] = (f16)t[tx][ty + i * 8];
}

// ---------------------------------------------------------------- embedding
__global__ __launch_bounds__(256) void embed_k(
    const int* __restrict__ src, const float* __restrict__ emb,
    const float* __restrict__ pe, float* __restrict__ x)
{
  const int gid = blockIdx.x * 256 + threadIdx.x;
  const int token = gid >> 6;
  const int d0 = (gid & 63) << 3;
  const int s = token & (Sx - 1);
  const int tk = src[token];
  const float* e = emb + (size_t)tk * Dm + d0;
  const float* p = pe + (size_t)s * Dm + d0;
  float* o = x + (size_t)token * Dm + d0;
  const float SC = 22.627416997969522f;  // sqrt(512)
  #pragma unroll
  for (int j = 0; j < 8; j++) o[j] = e[j] * SC + p[j];
}

// ---------------------------------------------------------------- mask bias
__global__ __launch_bounds__(256) void mask_k(
    const int* __restrict__ src, float* __restrict__ mb)
{
  const int i = blockIdx.x * 256 + threadIdx.x;
  mb[i] = (src[i] != 0) ? 0.f : -3.0e38f;
}

// ---------------------------------------------------------------- layernorm
template <typename OUT>
__global__ __launch_bounds__(256) void ln_k(
    const float* __restrict__ x, const float* __restrict__ sc,
    const float* __restrict__ bi, OUT* __restrict__ out)
{
  const int row = blockIdx.x * 4 + (threadIdx.x >> 6);
  const int l = threadIdx.x & 63;
  const float* px = x + (size_t)row * Dm + l * 8;
  float v[8];
  *(float4*)&v[0] = *(const float4*)px;
  *(float4*)&v[4] = *(const float4*)(px + 4);
  float s = 0.f;
  #pragma unroll
  for (int j = 0; j < 8; j++) s += v[j];
  #pragma unroll
  for (int m = 1; m < 64; m <<= 1) s += __shfl_xor(s, m);
  const float mu = s * (1.0f / 512.0f);
  float qv = 0.f;
  #pragma unroll
  for (int j = 0; j < 8; j++) { float d = v[j] - mu; qv += d * d; }
  #pragma unroll
  for (int m = 1; m < 64; m <<= 1) qv += __shfl_xor(qv, m);
  const float inv = rsqrtf(qv * (1.0f / 512.0f) + 1e-5f);
  float scv[8], biv[8];
  *(float4*)&scv[0] = *(const float4*)(sc + l * 8);
  *(float4*)&scv[4] = *(const float4*)(sc + l * 8 + 4);
  *(float4*)&biv[0] = *(const float4*)(bi + l * 8);
  *(float4*)&biv[4] = *(const float4*)(bi + l * 8 + 4);
  if constexpr (sizeof(OUT) == 2) {
    f16x8 o;
    #pragma unroll
    for (int j = 0; j < 8; j++) o[j] = (f16)((v[j] - mu) * inv * scv[j] + biv[j]);
    *(f16x8*)((f16*)out + (size_t)row * Dm + l * 8) = o;
  } else {
    float o[8];
    #pragma unroll
    for (int j = 0; j < 8; j++) o[j] = (v[j] - mu) * inv * scv[j] + biv[j];
    float* po = (float*)out + (size_t)row * Dm + l * 8;
    *(float4*)po = *(float4*)&o[0];
    *(float4*)(po + 4) = *(float4*)&o[4];
  }
}

// ---------------------------------------------------------------- GEMM
// C[4096][N] = A[4096][K] * Bt[N][K]^T; m97 structure + XCD swizzle (1D grid).
// MODE 0: out=f16 (QKV; z==2 writes V transposed per-head into O2)
// MODE 1: xio+=acc | 2: relu(acc+bias)->f16 | 3: xio += acc + bias
template <int BN, int MODE, int N, int K>
__global__ __launch_bounds__(256) void gemm_k(
    const f16* __restrict__ A,
    const f16* __restrict__ B0, const f16* __restrict__ B1, const f16* __restrict__ B2,
    f16* __restrict__ O0, f16* __restrict__ O1, f16* __restrict__ O2,
    float* __restrict__ xio, const float* __restrict__ bias)
{
  constexpr int BM = 128;
  constexpr int NF = (BN >= 32) ? (BN / 32) : 1;
  constexpr int NBM = NTOK / BM;            // 32
  constexpr int NBN = N / BN;
  constexpr int NZ = (MODE == 0) ? 3 : 1;
  constexpr int NB = NBM * NBN * NZ;        // multiple of 8
  __shared__ f16 lsA[BM * 64];
  __shared__ f16 lsB[BN * 64];
  const int tid = threadIdx.x;
  const int l = tid & 63, w = tid >> 6;
  const int lr = l & 15, lh = l >> 4;
  const int wm = w >> 1, wn = w & 1;
  const int bid = blockIdx.x;
  const int nid = (bid & 7) * (NB / 8) + (bid >> 3);
  const int z = nid / (NBM * NBN);
  const int rr = nid % (NBM * NBN);
  const int bm = rr / NBN, bn = rr % NBN;
  const f16* Bt = (z == 0) ? B0 : ((z == 1) ? B1 : B2);
  f16* Oz = (z == 0) ? O0 : O1;

  constexpr int ACH = (BM * 64) / (256 * 8);   // 4
  constexpr int BCH = (BN * 64) / (256 * 8);   // 1, 2 or 4
  const size_t rowA0 = (size_t)bm * BM;
  const size_t rowB0 = (size_t)bn * BN;

  f32x4 acc[4][NF] = {};
  constexpr int NT = K >> 6;
  for (int kt = 0; kt < NT; ++kt) {
    __syncthreads();
    #pragma unroll
    for (int i = 0; i < ACH; i++) {
      int c = i * 256 + tid;
      GLOAD_LDS16(A + (rowA0 + (c >> 3)) * K + kt * 64 + (c & 7) * 8, lsA + c * 8);
    }
    #pragma unroll
    for (int i = 0; i < BCH; i++) {
      int c = i * 256 + tid;
      GLOAD_LDS16(Bt + (rowB0 + (c >> 3)) * K + kt * 64 + (c & 7) * 8, lsB + c * 8);
    }
    __syncthreads();
    #pragma unroll
    for (int s = 0; s < 2; s++) {
      f16x8 af[4], bf[NF];
      #pragma unroll
      for (int mf = 0; mf < 4; mf++)
        af[mf] = *(const f16x8*)(lsA + (wm * 64 + mf * 16 + lr) * 64 + s * 32 + lh * 8);
      #pragma unroll
      for (int nf = 0; nf < NF; nf++)
        bf[nf] = *(const f16x8*)(lsB + (wn * (BN / 2) + nf * 16 + lr) * 64 + s * 32 + lh * 8);
      #pragma unroll
      for (int mf = 0; mf < 4; mf++)
        #pragma unroll
        for (int nf = 0; nf < NF; nf++)
          acc[mf][nf] = MFMA16(af[mf], bf[nf], acc[mf][nf]);
    }
  }

  #pragma unroll
  for (int mf = 0; mf < 4; mf++) {
    #pragma unroll
    for (int nf = 0; nf < NF; nf++) {
      const int token = bm * BM + wm * 64 + mf * 16 + lh * 4;
      const int ch = bn * BN + wn * (BN / 2) + nf * 16 + lr;
      if constexpr (MODE == 0) {
        if (z == 2) {
          // transposed per-head V write: vt[(b*8+h)*64+dv][s], 8B packed
          f16x4 o;
          #pragma unroll
          for (int r = 0; r < 4; r++) o[r] = (f16)acc[mf][nf][r];
          const int bb = token >> 11, ss = token & (Sx - 1);
          *(f16x4*)(O2 + ((size_t)((bb << 3) + (ch >> 6)) * 64 + (ch & 63)) * Sx + ss) = o;
        } else {
          #pragma unroll
          for (int r = 0; r < 4; r++)
            Oz[(size_t)(token + r) * N + ch] = (f16)acc[mf][nf][r];
        }
      } else {
        #pragma unroll
        for (int r = 0; r < 4; r++) {
          float v = acc[mf][nf][r];
          size_t idx = (size_t)(token + r) * N + ch;
          if constexpr (MODE == 1) {
            xio[idx] += v;
          } else if constexpr (MODE == 2) {
            v += bias[ch];
            O0[idx] = (f16)fmaxf(v, 0.f);
          } else {
            xio[idx] += v + bias[ch];
          }
        }
      }
    }
  }
}

// ---------------------------------------------------------------- attention
// Flash split-K, exp2 domain. 8 waves/block (512 thr); group g = w>>2 handles
// keys [g*1024, g*1024+1024); each wave owns 16 queries; merge via LDS.
// K/V LDS XOR-swizzled via pre-swizzled global source; mask = MFMA C-init.
__global__ __launch_bounds__(512) void attn_k(
    const f16* __restrict__ q, const f16* __restrict__ kk,
    const f16* __restrict__ vt, const float* __restrict__ maskb,
    f16* __restrict__ out)
{
  __shared__ f16 lsK[2][2][64 * 64];   // [grp][dbuf]
  __shared__ f16 lsV[2][2][64 * 64];
  const int tid = threadIdx.x;
  const int l = tid & 63, w = tid >> 6;
  const int lr = l & 15, lh = l >> 4;
  const int grp = w >> 2;
  const int t256 = tid & 255;
  const int bid = blockIdx.x;
  const int nid = ((bid & 7) << 6) + (bid >> 3);   // NB=512, chunk 64
  const int bh = nid >> 5;                          // 0..15
  const int qt = nid & 31;                          // 0..31
  const int b = bh >> 3, h = bh & 7;

  // Q frag, scaled by (1/sqrt(64)) * log2(e) -> scores in log2 domain
  const _Float16 QS = (_Float16)0.18033688f;
  f16x8 qf[2];
  #pragma unroll
  for (int s = 0; s < 2; s++) {
    size_t row = (size_t)(b * Sx + qt * 64 + (w & 3) * 16 + lr);
    f16x8 t = *(const f16x8*)(q + row * Dm + h * 64 + s * 32 + lh * 8);
    qf[s] = t * QS;
  }

  f32x4 oacc[4] = {};
  float mrun = -1e30f;
  float lrun = 0.f;

  auto stage = [&](int t, int pb) {
    #pragma unroll
    for (int i = 0; i < 2; i++) {
      int c = i * 256 + t256, r = c >> 3, g = c & 7, gs = g ^ (r & 7);
      GLOAD_LDS16(kk + (size_t)(b * Sx + t * 64 + r) * Dm + h * 64 + gs * 8,
                  &lsK[grp][pb][c * 8]);
      GLOAD_LDS16(vt + (size_t)(bh * 64 + r) * Sx + t * 64 + gs * 8,
                  &lsV[grp][pb][c * 8]);
    }
  };
  stage(grp * 16, 0);

  for (int i = 0; i < 16; ++i) {
    const int t = grp * 16 + i;
    const int cur = i & 1;
    __syncthreads();               // vmcnt(0) drain: buf[cur] ready
    if (i < 15) stage(t + 1, cur ^ 1);

    // ---- S^T = K @ Q^T, C-init = additive key-pad mask (log2 domain)
    f32x4 sacc[4];
    #pragma unroll
    for (int kf = 0; kf < 4; kf++)
      sacc[kf] = *(const f32x4*)(maskb + b * Sx + t * 64 + kf * 16 + lh * 4);
    __builtin_amdgcn_s_setprio(1);
    #pragma unroll
    for (int s = 0; s < 2; s++) {
      const int gk = (s * 4 + lh) ^ (lr & 7);
      #pragma unroll
      for (int kf = 0; kf < 4; kf++) {
        f16x8 a = *(const f16x8*)(&lsK[grp][cur][(kf * 16 + lr) * 64 + gk * 8]);
        sacc[kf] = MFMA16(a, qf[s], sacc[kf]);
      }
    }
    __builtin_amdgcn_s_setprio(0);

    // ---- online softmax (exp2); lane owns query col = lane&15
    float pmax = -3.0e38f;
    #pragma unroll
    for (int kf = 0; kf < 4; kf++)
      #pragma unroll
      for (int r = 0; r < 4; r++) pmax = fmaxf(pmax, sacc[kf][r]);
    pmax = fmaxf(pmax, __shfl_xor(pmax, 16));
    pmax = fmaxf(pmax, __shfl_xor(pmax, 32));
    if (!__all(pmax - mrun <= 8.0f)) {       // defer-max (T13, THR=8 log2)
      const float mnew = fmaxf(mrun, pmax);
      const float rs = fast_exp2(mrun - mnew);
      lrun *= rs;
      #pragma unroll
      for (int mf = 0; mf < 4; mf++) oacc[mf] *= rs;
      mrun = mnew;
    }
    float ps = 0.f;
    f16x8 pa[2];
    #pragma unroll
    for (int kf = 0; kf < 4; kf++)
      #pragma unroll
      for (int r = 0; r < 4; r++) {
        float p = fast_exp2(sacc[kf][r] - mrun);
        sacc[kf][r] = p;
        ps += p;
      }
    ps += __shfl_xor(ps, 16);
    ps += __shfl_xor(ps, 32);
    lrun += ps;
    // pack P^T: element jj -> key = 32s + 16*(jj>>2) + lh*4 + (jj&3)
    #pragma unroll
    for (int s = 0; s < 2; s++)
      #pragma unroll
      for (int jj = 0; jj < 8; jj++)
        pa[s][jj] = (f16)sacc[2 * s + (jj >> 2)][jj & 3];

    // ---- O^T += V^T @ P^T
    __builtin_amdgcn_s_setprio(1);
    #pragma unroll
    for (int s = 0; s < 2; s++) {
      const int g0 = (s * 4 + (lh >> 1)) ^ (lr & 7);
      const int g1 = ((s * 4 + (lh >> 1)) + 2) ^ (lr & 7);
      #pragma unroll
      for (int mf = 0; mf < 4; mf++) {
        union { f16x8 v8; f16x4 v4[2]; } u;
        const f16* vbase = &lsV[grp][cur][(mf * 16 + lr) * 64];
        u.v4[0] = *(const f16x4*)(vbase + g0 * 8 + (lh & 1) * 4);
        u.v4[1] = *(const f16x4*)(vbase + g1 * 8 + (lh & 1) * 4);
        oacc[mf] = MFMA16(u.v8, pa[s], oacc[mf]);
      }
    }
    __builtin_amdgcn_s_setprio(0);
  }

  // ---- merge the two key-groups via LDS (scratch reuses K/V tiles)
  __syncthreads();
  float* sO  = (float*)&lsK[0][0][0];     // 256 lanes * 16 f32 = 16 KB
  float* sML = (float*)&lsV[0][0][0];     // 256 lanes * 2  f32 =  2 KB
  const int wl = (w & 3) * 64 + l;
  if (grp == 1) {
    #pragma unroll
    for (int mf = 0; mf < 4; mf++)
      #pragma unroll
      for (int r = 0; r < 4; r++) sO[wl * 16 + mf * 4 + r] = oacc[mf][r];
    sML[wl * 2] = mrun;
    sML[wl * 2 + 1] = lrun;
  }
  __syncthreads();
  if (grp == 0) {
    const float m1 = sML[wl * 2], l1 = sML[wl * 2 + 1];
    const float mm = fmaxf(mrun, m1);
    const float s0 = fast_exp2(mrun - mm), s1 = fast_exp2(m1 - mm);
    const float inv = 1.f / (lrun * s0 + l1 * s1);
    size_t row = (size_t)(b * Sx + qt * 64 + (w & 3) * 16 + lr);
    #pragma unroll
    for (int mf = 0; mf < 4; mf++) {
      f16x4 o;
      #pragma unroll
      for (int r = 0; r < 4; r++)
        o[r] = (f16)((oacc[mf][r] * s0 + sO[wl * 16 + mf * 4 + r] * s1) * inv);
      *(f16x4*)(out + row * Dm + h * 64 + mf * 16 + lh * 4) = o;
    }
  }
}

// ---------------------------------------------------------------- launch
extern "C" void kernel_launch(void* const* d_in, const int* in_sizes, int n_in,
                              void* d_out, int out_size, void* d_ws, size_t ws_size,
                              hipStream_t stream)
{
  (void)in_sizes; (void)n_in; (void)out_size; (void)ws_size;
  const int*   src  = (const int*)d_in[0];
  const float* emb  = (const float*)d_in[1];
  const float* pe   = (const float*)d_in[2];
  const float* WQ   = (const float*)d_in[3];
  const float* WK   = (const float*)d_in[4];
  const float* WV   = (const float*)d_in[5];
  const float* WO   = (const float*)d_in[6];
  const float* W1   = (const float*)d_in[7];
  const float* b1   = (const float*)d_in[8];
  const float* W2   = (const float*)d_in[9];
  const float* b2   = (const float*)d_in[10];
  const float* ln1s = (const float*)d_in[11];
  const float* ln1b = (const float*)d_in[12];
  const float* ln2s = (const float*)d_in[13];
  const float* ln2b = (const float*)d_in[14];
  const float* fns  = (const float*)d_in[15];
  const float* fnb  = (const float*)d_in[16];

  char* ws = (char*)d_ws;
  const size_t DD = (size_t)Dm * Dm;
  const size_t DF = (size_t)Dm * DFFm;
  f16* wtQ = (f16*)(ws);
  f16* wtK = wtQ + Lc * DD;
  f16* wtV = wtK + Lc * DD;
  f16* wtO = wtV + Lc * DD;
  f16* wt1 = wtO + Lc * DD;
  f16* wt2 = wt1 + Lc * DF;
  float* x  = (float*)(wt2 + Lc * DF);
  f16* hbuf = (f16*)(x + (size_t)NTOK * Dm);
  f16* qb   = hbuf + (size_t)NTOK * Dm;
  f16* kb   = qb + (size_t)NTOK * Dm;
  f16* vtb  = kb + (size_t)NTOK * Dm;          // [16][64][2048] per-head V^T
  f16* attn = vtb + (size_t)NTOK * Dm;
  f16* ff   = attn + (size_t)NTOK * Dm;        // [4096][2048]
  float* maskb = (float*)(ff + (size_t)NTOK * DFFm);  // [2][2048]

  const dim3 tb(32, 8);
  transpose_cvt<<<dim3(16, 16, Lc), tb, 0, stream>>>(WQ, wtQ, Dm, Dm);
  transpose_cvt<<<dim3(16, 16, Lc), tb, 0, stream>>>(WK, wtK, Dm, Dm);
  transpose_cvt<<<dim3(16, 16, Lc), tb, 0, stream>>>(WV, wtV, Dm, Dm);
  transpose_cvt<<<dim3(16, 16, Lc), tb, 0, stream>>>(WO, wtO, Dm, Dm);
  transpose_cvt<<<dim3(64, 16, Lc), tb, 0, stream>>>(W1, wt1, Dm, DFFm);
  transpose_cvt<<<dim3(16, 64, Lc), tb, 0, stream>>>(W2, wt2, DFFm, Dm);

  embed_k<<<1024, 256, 0, stream>>>(src, emb, pe, x);
  mask_k<<<16, 256, 0, stream>>>(src, maskb);

  for (int l = 0; l < Lc; l++) {
    const f16* wq = wtQ + (size_t)l * DD;
    const f16* wk = wtK + (size_t)l * DD;
    const f16* wv = wtV + (size_t)l * DD;
    const f16* wo = wtO + (size_t)l * DD;
    const f16* w1 = wt1 + (size_t)l * DF;
    const f16* w2 = wt2 + (size_t)l * DF;

    ln_k<f16><<<1024, 256, 0, stream>>>(x, ln1s + l * Dm, ln1b + l * Dm, hbuf);
    gemm_k<64, 0, 512, 512><<<768, 256, 0, stream>>>(
        hbuf, wq, wk, wv, qb, kb, vtb, nullptr, nullptr);
    attn_k<<<512, 512, 0, stream>>>(qb, kb, vtb, maskb, attn);
    gemm_k<32, 1, 512, 512><<<512, 256, 0, stream>>>(
        attn, wo, wo, wo, nullptr, nullptr, nullptr, x, nullptr);
    ln_k<f16><<<1024, 256, 0, stream>>>(x, ln2s + l * Dm, ln2b + l * Dm, hbuf);
    gemm_k<128, 2, 2048, 512><<<512, 256, 0, stream>>>(
        hbuf, w1, w1, w1, ff, ff, ff, nullptr, b1 + (size_t)l * DFFm);
    gemm_k<32, 3, 512, 2048><<<512, 256, 0, stream>>>(
        ff, w2, w2, w2, nullptr, nullptr, nullptr, x, b2 + (size_t)l * Dm);
  }

  ln_k<float><<<1024, 256, 0, stream>>>(x, fns, fnb, (float*)d_out);
}

// Round 5
// 734.858 us; speedup vs baseline: 2.9504x; 1.0107x over previous
//
#include <hip/hip_runtime.h>

// ---------------------------------------------------------------------------
// Transformer encoder (B=2, S=2048, D=512, H=8, DK=64, DFF=2048, L=6), fp16
// MFMA compute, f32 residual stream.
// R5: GEMMs double-buffered (stage-next overlaps compute, 1 barrier/iter);
// attn: row-sum via MFMA ones-trick, v_max3 pmax tree, sigma-permuted V^T
// storage -> PV reads are single ds_read_b128.
// ---------------------------------------------------------------------------

typedef _Float16 f16;
typedef _Float16 f16x8 __attribute__((ext_vector_type(8)));
typedef _Float16 f16x4 __attribute__((ext_vector_type(4)));
typedef float    f32x4 __attribute__((ext_vector_type(4)));

#define MFMA16(a, b, c) __builtin_amdgcn_mfma_f32_16x16x32_f16((a), (b), (c), 0, 0, 0)
#define GLOAD_LDS16(GP, LP)                                        \
  __builtin_amdgcn_global_load_lds(                                \
      (const __attribute__((address_space(1))) void*)(GP),         \
      (__attribute__((address_space(3))) void*)(LP), 16, 0, 0)

__device__ inline float fast_exp2(float x) {
#if __has_builtin(__builtin_amdgcn_exp2f)
  return __builtin_amdgcn_exp2f(x);
#else
  return exp2f(x);
#endif
}

static constexpr int Dm  = 512;
static constexpr int Sx  = 2048;
static constexpr int NTOK = 4096;   // B*S
static constexpr int DFFm = 2048;
static constexpr int Lc  = 6;

// ---------------------------------------------------------------- transpose+cvt
__global__ __launch_bounds__(256) void transpose_cvt(
    const float* __restrict__ in, f16* __restrict__ out, int R, int C)
{
  __shared__ float t[32][33];
  const int z = blockIdx.z;
  const float* src = in + (size_t)z * R * C;
  f16* dst = out + (size_t)z * R * C;
  const int r0 = blockIdx.y * 32, c0 = blockIdx.x * 32;
  const int tx = threadIdx.x, ty = threadIdx.y;
  #pragma unroll
  for (int i = 0; i < 4; i++)
    t[ty + i * 8][tx] = src[(size_t)(r0 + ty + i * 8) * C + c0 + tx];
  __syncthreads();
  #pragma unroll
  for (int i = 0; i < 4; i++)
    dst[(size_t)(c0 + ty + i * 8) * R + r0 + tx] = (f16)t[tx][ty + i * 8];
}

// ---------------------------------------------------------------- embedding
__global__ __launch_bounds__(256) void embed_k(
    const int* __restrict__ src, const float* __restrict__ emb,
    const float* __restrict__ pe, float* __restrict__ x)
{
  const int gid = blockIdx.x * 256 + threadIdx.x;
  const int token = gid >> 6;
  const int d0 = (gid & 63) << 3;
  const int s = token & (Sx - 1);
  const int tk = src[token];
  const float* e = emb + (size_t)tk * Dm + d0;
  const float* p = pe + (size_t)s * Dm + d0;
  float* o = x + (size_t)token * Dm + d0;
  const float SC = 22.627416997969522f;  // sqrt(512)
  #pragma unroll
  for (int j = 0; j < 8; j++) o[j] = e[j] * SC + p[j];
}

// ---------------------------------------------------------------- mask bias
__global__ __launch_bounds__(256) void mask_k(
    const int* __restrict__ src, float* __restrict__ mb)
{
  const int i = blockIdx.x * 256 + threadIdx.x;
  mb[i] = (src[i] != 0) ? 0.f : -3.0e38f;
}

// ---------------------------------------------------------------- layernorm
template <typename OUT>
__global__ __launch_bounds__(256) void ln_k(
    const float* __restrict__ x, const float* __restrict__ sc,
    const float* __restrict__ bi, OUT* __restrict__ out)
{
  const int row = blockIdx.x * 4 + (threadIdx.x >> 6);
  const int l = threadIdx.x & 63;
  const float* px = x + (size_t)row * Dm + l * 8;
  float v[8];
  *(float4*)&v[0] = *(const float4*)px;
  *(float4*)&v[4] = *(const float4*)(px + 4);
  float s = 0.f;
  #pragma unroll
  for (int j = 0; j < 8; j++) s += v[j];
  #pragma unroll
  for (int m = 1; m < 64; m <<= 1) s += __shfl_xor(s, m);
  const float mu = s * (1.0f / 512.0f);
  float qv = 0.f;
  #pragma unroll
  for (int j = 0; j < 8; j++) { float d = v[j] - mu; qv += d * d; }
  #pragma unroll
  for (int m = 1; m < 64; m <<= 1) qv += __shfl_xor(qv, m);
  const float inv = rsqrtf(qv * (1.0f / 512.0f) + 1e-5f);
  float scv[8], biv[8];
  *(float4*)&scv[0] = *(const float4*)(sc + l * 8);
  *(float4*)&scv[4] = *(const float4*)(sc + l * 8 + 4);
  *(float4*)&biv[0] = *(const float4*)(bi + l * 8);
  *(float4*)&biv[4] = *(const float4*)(bi + l * 8 + 4);
  if constexpr (sizeof(OUT) == 2) {
    f16x8 o;
    #pragma unroll
    for (int j = 0; j < 8; j++) o[j] = (f16)((v[j] - mu) * inv * scv[j] + biv[j]);
    *(f16x8*)((f16*)out + (size_t)row * Dm + l * 8) = o;
  } else {
    float o[8];
    #pragma unroll
    for (int j = 0; j < 8; j++) o[j] = (v[j] - mu) * inv * scv[j] + biv[j];
    float* po = (float*)out + (size_t)row * Dm + l * 8;
    *(float4*)po = *(float4*)&o[0];
    *(float4*)(po + 4) = *(float4*)&o[4];
  }
}

// ---------------------------------------------------------------- GEMM
// C[4096][N] = A[4096][K] * Bt[N][K]^T; double-buffered LDS, 1 barrier/iter,
// gload_lds(16B) staging, XCD-swizzled 1D grid.
// MODE 0: out=f16 (QKV; z==2 writes sigma-permuted per-head V^T into O2)
// MODE 1: xio+=acc | 2: relu(acc+bias)->f16 | 3: xio += acc + bias
template <int BN, int MODE, int N, int K>
__global__ __launch_bounds__(256) void gemm_k(
    const f16* __restrict__ A,
    const f16* __restrict__ B0, const f16* __restrict__ B1, const f16* __restrict__ B2,
    f16* __restrict__ O0, f16* __restrict__ O1, f16* __restrict__ O2,
    float* __restrict__ xio, const float* __restrict__ bias)
{
  constexpr int BM = 128;
  constexpr int NF = BN / 32;
  constexpr int NBM = NTOK / BM;            // 32
  constexpr int NBN = N / BN;
  constexpr int NZ = (MODE == 0) ? 3 : 1;
  constexpr int NB = NBM * NBN * NZ;        // multiple of 8
  __shared__ f16 lsA[2][BM * 64];
  __shared__ f16 lsB[2][BN * 64];
  const int tid = threadIdx.x;
  const int l = tid & 63, w = tid >> 6;
  const int lr = l & 15, lh = l >> 4;
  const int wm = w >> 1, wn = w & 1;
  const int bid = blockIdx.x;
  const int nid = (bid & 7) * (NB / 8) + (bid >> 3);
  const int z = nid / (NBM * NBN);
  const int rr = nid % (NBM * NBN);
  const int bm = rr / NBN, bn = rr % NBN;
  const f16* Bt = (z == 0) ? B0 : ((z == 1) ? B1 : B2);
  f16* Oz = (z == 0) ? O0 : O1;

  constexpr int ACH = (BM * 64) / (256 * 8);   // 4
  constexpr int BCH = (BN * 64) / (256 * 8);   // 1, 2 or 4
  const size_t rowA0 = (size_t)bm * BM;
  const size_t rowB0 = (size_t)bn * BN;

  auto stage = [&](int kt, int pb) {
    #pragma unroll
    for (int i = 0; i < ACH; i++) {
      int c = i * 256 + tid;
      GLOAD_LDS16(A + (rowA0 + (c >> 3)) * K + kt * 64 + (c & 7) * 8, &lsA[pb][c * 8]);
    }
    #pragma unroll
    for (int i = 0; i < BCH; i++) {
      int c = i * 256 + tid;
      GLOAD_LDS16(Bt + (rowB0 + (c >> 3)) * K + kt * 64 + (c & 7) * 8, &lsB[pb][c * 8]);
    }
  };

  f32x4 acc[4][NF] = {};
  stage(0, 0);
  constexpr int NT = K >> 6;
  for (int kt = 0; kt < NT; ++kt) {
    const int cur = kt & 1;
    __syncthreads();                 // drains vmcnt: buf[cur] ready
    if (kt + 1 < NT) stage(kt + 1, cur ^ 1);   // overlaps with compute below
    #pragma unroll
    for (int s = 0; s < 2; s++) {
      f16x8 af[4], bf[NF];
      #pragma unroll
      for (int mf = 0; mf < 4; mf++)
        af[mf] = *(const f16x8*)(&lsA[cur][(wm * 64 + mf * 16 + lr) * 64 + s * 32 + lh * 8]);
      #pragma unroll
      for (int nf = 0; nf < NF; nf++)
        bf[nf] = *(const f16x8*)(&lsB[cur][(wn * (BN / 2) + nf * 16 + lr) * 64 + s * 32 + lh * 8]);
      #pragma unroll
      for (int mf = 0; mf < 4; mf++)
        #pragma unroll
        for (int nf = 0; nf < NF; nf++)
          acc[mf][nf] = MFMA16(af[mf], bf[nf], acc[mf][nf]);
    }
  }

  #pragma unroll
  for (int mf = 0; mf < 4; mf++) {
    #pragma unroll
    for (int nf = 0; nf < NF; nf++) {
      const int token = bm * BM + wm * 64 + mf * 16 + lh * 4;
      const int ch = bn * BN + wn * (BN / 2) + nf * 16 + lr;
      if constexpr (MODE == 0) {
        if (z == 2) {
          // sigma-permuted transposed per-head V: col = (ss&~31)|lhk*8|a*4 (+r)
          f16x4 o;
          #pragma unroll
          for (int r = 0; r < 4; r++) o[r] = (f16)acc[mf][nf][r];
          const int bb = token >> 11, ss = token & (Sx - 1);
          const int scol = (ss & ~31) | (((ss >> 2) & 3) << 3) | (((ss >> 4) & 1) << 2);
          *(f16x4*)(O2 + ((size_t)((bb << 3) + (ch >> 6)) * 64 + (ch & 63)) * Sx + scol) = o;
        } else {
          #pragma unroll
          for (int r = 0; r < 4; r++)
            Oz[(size_t)(token + r) * N + ch] = (f16)acc[mf][nf][r];
        }
      } else {
        #pragma unroll
        for (int r = 0; r < 4; r++) {
          float v = acc[mf][nf][r];
          size_t idx = (size_t)(token + r) * N + ch;
          if constexpr (MODE == 1) {
            xio[idx] += v;
          } else if constexpr (MODE == 2) {
            v += bias[ch];
            O0[idx] = (f16)fmaxf(v, 0.f);
          } else {
            xio[idx] += v + bias[ch];
          }
        }
      }
    }
  }
}

// ---------------------------------------------------------------- attention
// Flash split-K, exp2 domain. 8 waves/block; grp = w>>2 handles 1024 keys;
// 16 queries/wave; LDS merge. K/V XOR-swizzled via pre-swizzled global src;
// mask = MFMA C-init; row-sum via MFMA ones-trick; V^T sigma-permuted so PV
// A-operand reads are single b128.
__global__ __launch_bounds__(512) void attn_k(
    const f16* __restrict__ q, const f16* __restrict__ kk,
    const f16* __restrict__ vt, const float* __restrict__ maskb,
    f16* __restrict__ out)
{
  __shared__ f16 lsK[2][2][64 * 64];   // [grp][dbuf]
  __shared__ f16 lsV[2][2][64 * 64];
  const int tid = threadIdx.x;
  const int l = tid & 63, w = tid >> 6;
  const int lr = l & 15, lh = l >> 4;
  const int grp = w >> 2;
  const int t256 = tid & 255;
  const int bid = blockIdx.x;
  const int nid = ((bid & 7) << 6) + (bid >> 3);   // NB=512, chunk 64
  const int bh = nid >> 5;                          // 0..15
  const int qt = nid & 31;                          // 0..31
  const int b = bh >> 3, h = bh & 7;

  // Q frag, scaled by (1/sqrt(64)) * log2(e) -> scores in log2 domain
  const _Float16 QS = (_Float16)0.18033688f;
  f16x8 qf[2];
  #pragma unroll
  for (int s = 0; s < 2; s++) {
    size_t row = (size_t)(b * Sx + qt * 64 + (w & 3) * 16 + lr);
    f16x8 t = *(const f16x8*)(q + row * Dm + h * 64 + s * 32 + lh * 8);
    qf[s] = t * QS;
  }

  const f16x8 ones = {(f16)1, (f16)1, (f16)1, (f16)1,
                      (f16)1, (f16)1, (f16)1, (f16)1};
  f32x4 oacc[4] = {};
  f32x4 sumacc = {};
  float mrun = -1e30f;

  auto stage = [&](int t, int pb) {
    #pragma unroll
    for (int i = 0; i < 2; i++) {
      int c = i * 256 + t256, r = c >> 3, g = c & 7, gs = g ^ (r & 7);
      GLOAD_LDS16(kk + (size_t)(b * Sx + t * 64 + r) * Dm + h * 64 + gs * 8,
                  &lsK[grp][pb][c * 8]);
      GLOAD_LDS16(vt + (size_t)(bh * 64 + r) * Sx + t * 64 + gs * 8,
                  &lsV[grp][pb][c * 8]);
    }
  };
  stage(grp * 16, 0);

  for (int i = 0; i < 16; ++i) {
    const int t = grp * 16 + i;
    const int cur = i & 1;
    __syncthreads();               // vmcnt(0) drain: buf[cur] ready
    if (i < 15) stage(t + 1, cur ^ 1);

    // ---- S^T = K @ Q^T, C-init = additive key-pad mask (log2 domain)
    f32x4 sacc[4];
    #pragma unroll
    for (int kf = 0; kf < 4; kf++)
      sacc[kf] = *(const f32x4*)(maskb + b * Sx + t * 64 + kf * 16 + lh * 4);
    __builtin_amdgcn_s_setprio(1);
    #pragma unroll
    for (int s = 0; s < 2; s++) {
      const int gk = (s * 4 + lh) ^ (lr & 7);
      #pragma unroll
      for (int kf = 0; kf < 4; kf++) {
        f16x8 a = *(const f16x8*)(&lsK[grp][cur][(kf * 16 + lr) * 64 + gk * 8]);
        sacc[kf] = MFMA16(a, qf[s], sacc[kf]);
      }
    }
    __builtin_amdgcn_s_setprio(0);

    // ---- online softmax (exp2); lane owns query col = lane&15
    float pmax;
    {
      float t0 = fmaxf(fmaxf(sacc[0][0], sacc[0][1]), sacc[0][2]);
      float t1 = fmaxf(fmaxf(sacc[0][3], sacc[1][0]), sacc[1][1]);
      float t2 = fmaxf(fmaxf(sacc[1][2], sacc[1][3]), sacc[2][0]);
      float t3 = fmaxf(fmaxf(sacc[2][1], sacc[2][2]), sacc[2][3]);
      float t4 = fmaxf(fmaxf(sacc[3][0], sacc[3][1]), sacc[3][2]);
      float u0 = fmaxf(fmaxf(t0, t1), sacc[3][3]);
      float u1 = fmaxf(fmaxf(t2, t3), t4);
      pmax = fmaxf(u0, u1);
    }
    pmax = fmaxf(pmax, __shfl_xor(pmax, 16));
    pmax = fmaxf(pmax, __shfl_xor(pmax, 32));
    if (!__all(pmax - mrun <= 8.0f)) {       // defer-max (T13, THR=8 log2)
      const float mnew = fmaxf(mrun, pmax);
      const float rs = fast_exp2(mrun - mnew);
      sumacc *= rs;
      #pragma unroll
      for (int mf = 0; mf < 4; mf++) oacc[mf] *= rs;
      mrun = mnew;
    }
    #pragma unroll
    for (int kf = 0; kf < 4; kf++)
      #pragma unroll
      for (int r = 0; r < 4; r++)
        sacc[kf][r] = fast_exp2(sacc[kf][r] - mrun);
    // pack P^T: element jj -> key = 32s + 16*(jj>>2) + lh*4 + (jj&3)
    f16x8 pa[2];
    #pragma unroll
    for (int s = 0; s < 2; s++)
      #pragma unroll
      for (int jj = 0; jj < 8; jj++)
        pa[s][jj] = (f16)sacc[2 * s + (jj >> 2)][jj & 3];
    // row-sum via MFMA ones-trick (replaces 16 adds + 2 shuffles)
    sumacc = MFMA16(ones, pa[0], sumacc);
    sumacc = MFMA16(ones, pa[1], sumacc);

    // ---- O^T += V^T @ P^T (sigma-permuted V: single b128 per mf,s)
    __builtin_amdgcn_s_setprio(1);
    #pragma unroll
    for (int s = 0; s < 2; s++) {
      const int gv = (4 * s + lh) ^ (lr & 7);
      #pragma unroll
      for (int mf = 0; mf < 4; mf++) {
        f16x8 vv = *(const f16x8*)(&lsV[grp][cur][(mf * 16 + lr) * 64 + gv * 8]);
        oacc[mf] = MFMA16(vv, pa[s], oacc[mf]);
      }
    }
    __builtin_amdgcn_s_setprio(0);
  }

  // ---- merge the two key-groups via LDS (scratch reuses K/V tiles)
  const float lrun = sumacc[0];
  __syncthreads();
  float* sO  = (float*)&lsK[0][0][0];     // 256 lanes * 16 f32 = 16 KB
  float* sML = (float*)&lsV[0][0][0];     // 256 lanes * 2  f32 =  2 KB
  const int wl = (w & 3) * 64 + l;
  if (grp == 1) {
    #pragma unroll
    for (int mf = 0; mf < 4; mf++)
      #pragma unroll
      for (int r = 0; r < 4; r++) sO[wl * 16 + mf * 4 + r] = oacc[mf][r];
    sML[wl * 2] = mrun;
    sML[wl * 2 + 1] = lrun;
  }
  __syncthreads();
  if (grp == 0) {
    const float m1 = sML[wl * 2], l1 = sML[wl * 2 + 1];
    const float mm = fmaxf(mrun, m1);
    const float s0 = fast_exp2(mrun - mm), s1 = fast_exp2(m1 - mm);
    const float inv = 1.f / (lrun * s0 + l1 * s1);
    size_t row = (size_t)(b * Sx + qt * 64 + (w & 3) * 16 + lr);
    #pragma unroll
    for (int mf = 0; mf < 4; mf++) {
      f16x4 o;
      #pragma unroll
      for (int r = 0; r < 4; r++)
        o[r] = (f16)((oacc[mf][r] * s0 + sO[wl * 16 + mf * 4 + r] * s1) * inv);
      *(f16x4*)(out + row * Dm + h * 64 + mf * 16 + lh * 4) = o;
    }
  }
}

// ---------------------------------------------------------------- launch
extern "C" void kernel_launch(void* const* d_in, const int* in_sizes, int n_in,
                              void* d_out, int out_size, void* d_ws, size_t ws_size,
                              hipStream_t stream)
{
  (void)in_sizes; (void)n_in; (void)out_size; (void)ws_size;
  const int*   src  = (const int*)d_in[0];
  const float* emb  = (const float*)d_in[1];
  const float* pe   = (const float*)d_in[2];
  const float* WQ   = (const float*)d_in[3];
  const float* WK   = (const float*)d_in[4];
  const float* WV   = (const float*)d_in[5];
  const float* WO   = (const float*)d_in[6];
  const float* W1   = (const float*)d_in[7];
  const float* b1   = (const float*)d_in[8];
  const float* W2   = (const float*)d_in[9];
  const float* b2   = (const float*)d_in[10];
  const float* ln1s = (const float*)d_in[11];
  const float* ln1b = (const float*)d_in[12];
  const float* ln2s = (const float*)d_in[13];
  const float* ln2b = (const float*)d_in[14];
  const float* fns  = (const float*)d_in[15];
  const float* fnb  = (const float*)d_in[16];

  char* ws = (char*)d_ws;
  const size_t DD = (size_t)Dm * Dm;
  const size_t DF = (size_t)Dm * DFFm;
  f16* wtQ = (f16*)(ws);
  f16* wtK = wtQ + Lc * DD;
  f16* wtV = wtK + Lc * DD;
  f16* wtO = wtV + Lc * DD;
  f16* wt1 = wtO + Lc * DD;
  f16* wt2 = wt1 + Lc * DF;
  float* x  = (float*)(wt2 + Lc * DF);
  f16* hbuf = (f16*)(x + (size_t)NTOK * Dm);
  f16* qb   = hbuf + (size_t)NTOK * Dm;
  f16* kb   = qb + (size_t)NTOK * Dm;
  f16* vtb  = kb + (size_t)NTOK * Dm;          // [16][64][2048] sigma-permuted V^T
  f16* attn = vtb + (size_t)NTOK * Dm;
  f16* ff   = attn + (size_t)NTOK * Dm;        // [4096][2048]
  float* maskb = (float*)(ff + (size_t)NTOK * DFFm);  // [2][2048]

  const dim3 tb(32, 8);
  transpose_cvt<<<dim3(16, 16, Lc), tb, 0, stream>>>(WQ, wtQ, Dm, Dm);
  transpose_cvt<<<dim3(16, 16, Lc), tb, 0, stream>>>(WK, wtK, Dm, Dm);
  transpose_cvt<<<dim3(16, 16, Lc), tb, 0, stream>>>(WV, wtV, Dm, Dm);
  transpose_cvt<<<dim3(16, 16, Lc), tb, 0, stream>>>(WO, wtO, Dm, Dm);
  transpose_cvt<<<dim3(64, 16, Lc), tb, 0, stream>>>(W1, wt1, Dm, DFFm);
  transpose_cvt<<<dim3(16, 64, Lc), tb, 0, stream>>>(W2, wt2, DFFm, Dm);

  embed_k<<<1024, 256, 0, stream>>>(src, emb, pe, x);
  mask_k<<<16, 256, 0, stream>>>(src, maskb);

  for (int l = 0; l < Lc; l++) {
    const f16* wq = wtQ + (size_t)l * DD;
    const f16* wk = wtK + (size_t)l * DD;
    const f16* wv = wtV + (size_t)l * DD;
    const f16* wo = wtO + (size_t)l * DD;
    const f16* w1 = wt1 + (size_t)l * DF;
    const f16* w2 = wt2 + (size_t)l * DF;

    ln_k<f16><<<1024, 256, 0, stream>>>(x, ln1s + l * Dm, ln1b + l * Dm, hbuf);
    gemm_k<64, 0, 512, 512><<<768, 256, 0, stream>>>(
        hbuf, wq, wk, wv, qb, kb, vtb, nullptr, nullptr);
    attn_k<<<512, 512, 0, stream>>>(qb, kb, vtb, maskb, attn);
    gemm_k<32, 1, 512, 512><<<512, 256, 0, stream>>>(
        attn, wo, wo, wo, nullptr, nullptr, nullptr, x, nullptr);
    ln_k<f16><<<1024, 256, 0, stream>>>(x, ln2s + l * Dm, ln2b + l * Dm, hbuf);
    gemm_k<128, 2, 2048, 512><<<512, 256, 0, stream>>>(
        hbuf, w1, w1, w1, ff, ff, ff, nullptr, b1 + (size_t)l * DFFm);
    gemm_k<32, 3, 512, 2048><<<512, 256, 0, stream>>>(
        ff, w2, w2, w2, nullptr, nullptr, nullptr, x, b2 + (size_t)l * Dm);
  }

  ln_k<float><<<1024, 256, 0, stream>>>(x, fns, fnb, (float*)d_out);
}